// Round 14
// baseline (280.618 us; speedup 1.0000x reference)
//
#include <hip/hip_runtime.h>
#include <math.h>

#define N 4096
#define NF 512
#define NH 128
#define NC 16
#define CSPLIT 8

typedef unsigned short u16;
typedef __attribute__((ext_vector_type(4))) unsigned short u16x4;
typedef __attribute__((ext_vector_type(8))) short bf16x8;
typedef __attribute__((ext_vector_type(4))) float f32x4;

__device__ __forceinline__ u16 hi16(float v) {
  return (u16)(__float_as_uint(v) >> 16);
}
__device__ __forceinline__ float hif(float v) {
  return __uint_as_float(__float_as_uint(v) & 0xffff0000u);
}
// B-plane swizzled u16 index: byte = col*16 ^ ((col&0x38)<<1)
__device__ __forceinline__ int idxB(int col) {
  return (col * 8) ^ (col & 0x38);
}

// ---------------------------------------------------------------------------
// k_wc: Wc2[k][j][4] = {sum_t Wa_k[j,t]*Wagg[k*64+t, c]}  (float4-aligned)
// ---------------------------------------------------------------------------
__global__ void k_wc(const float* __restrict__ Wa1, const float* __restrict__ Wa2,
                     const float* __restrict__ Wa3, const float* __restrict__ Wagg,
                     const float* __restrict__ ba1, const float* __restrict__ ba2,
                     const float* __restrict__ ba3, const float* __restrict__ bagg,
                     float* __restrict__ Wc2, float* __restrict__ bz) {
  int idx = blockIdx.x * 256 + threadIdx.x;
  if (idx < 3 * N) {
    int k = idx >> 12;
    int j = idx & (N - 1);
    const float* Wa = (k == 0) ? Wa1 : (k == 1) ? Wa2 : Wa3;
    float a0 = 0.f, a1 = 0.f, a2 = 0.f;
    for (int t = 0; t < 64; ++t) {
      float w = Wa[j * 64 + t];
      const float* wg = Wagg + (k * 64 + t) * 3;
      a0 += w * wg[0]; a1 += w * wg[1]; a2 += w * wg[2];
    }
    float4 o = {a0, a1, a2, 0.f};
    *(float4*)&Wc2[(k * N + j) * 4] = o;
  }
  if (blockIdx.x == 0 && threadIdx.x < 3) {
    int c = threadIdx.x;
    float acc = bagg[c];
    for (int t = 0; t < 64; ++t) {
      acc += ba1[t] * Wagg[t * 3 + c]
           + ba2[t] * Wagg[(64 + t) * 3 + c]
           + ba3[t] * Wagg[(128 + t) * 3 + c];
    }
    bz[c] = acc;
  }
}

// ---------------------------------------------------------------------------
// k_z4p: one matrix's z4 partial.  Grid 1024 blocks x 256 threads.
// ---------------------------------------------------------------------------
__global__ __launch_bounds__(256) void k_z4p(const float* __restrict__ A,
                                             const float* __restrict__ Wck,
                                             float* __restrict__ zpk) {
  __shared__ float red[4][3][4];
  int r0 = blockIdx.x * 4;
  int tid = threadIdx.x;
  int lane = tid & 63, wv = tid >> 6;
  float acc[4][3];
#pragma unroll
  for (int r = 0; r < 4; ++r) { acc[r][0] = 0.f; acc[r][1] = 0.f; acc[r][2] = 0.f; }
#pragma unroll
  for (int s = 0; s < 4; ++s) {
    int j4 = s * 1024 + tid * 4;
    const float4 w0 = *(const float4*)&Wck[(j4 + 0) * 4];
    const float4 w1 = *(const float4*)&Wck[(j4 + 1) * 4];
    const float4 w2 = *(const float4*)&Wck[(j4 + 2) * 4];
    const float4 w3 = *(const float4*)&Wck[(j4 + 3) * 4];
#pragma unroll
    for (int r = 0; r < 4; ++r) {
      const float4 a = *(const float4*)&A[(size_t)(r0 + r) * N + j4];
      acc[r][0] += a.x * w0.x + a.y * w1.x + a.z * w2.x + a.w * w3.x;
      acc[r][1] += a.x * w0.y + a.y * w1.y + a.z * w2.y + a.w * w3.y;
      acc[r][2] += a.x * w0.z + a.y * w1.z + a.z * w2.z + a.w * w3.z;
    }
  }
#pragma unroll
  for (int r = 0; r < 4; ++r) {
#pragma unroll
    for (int c = 0; c < 3; ++c) {
      float v = acc[r][c];
      v += __shfl_xor(v, 1);
      v += __shfl_xor(v, 2);
      v += __shfl_xor(v, 4);
      v += __shfl_xor(v, 8);
      v += __shfl_xor(v, 16);
      v += __shfl_xor(v, 32);
      if (lane == 0) red[r][c][wv] = v;
    }
  }
  __syncthreads();
  if (tid < 12) {
    int r = tid / 3; int c = tid - 3 * r;
    zpk[(r0 + r) * 12 + c] =
        red[r][c][0] + red[r][c][1] + red[r][c][2] + red[r][c][3];
  }
}

// ---------------------------------------------------------------------------
// k_nz: z4 = sum of 3 matrix partials + bz; 3-way softmax -> nz
// ---------------------------------------------------------------------------
__global__ void k_nz(const float* __restrict__ zp, const float* __restrict__ bz,
                     float* __restrict__ nz) {
  int row = blockIdx.x * 256 + threadIdx.x;
  const float* p = zp + row * 12;
  float z0 = p[0] + p[3] + p[6] + bz[0];
  float z1 = p[1] + p[4] + p[7] + bz[1];
  float z2 = p[2] + p[5] + p[8] + bz[2];
  float m = fmaxf(z0, fmaxf(z1, z2));
  float e0 = __expf(z0 - m), e1 = __expf(z1 - m), e2 = __expf(z2 - m);
  float s = e0 + e1 + e2;
  float* o = nz + row * 3;
  o[0] = e0 / s; o[1] = e1 / s; o[2] = e2 / s;
}

// ---------------------------------------------------------------------------
// k_adj: adj[i,j] = A0*nz[j,0] + A1*nz[j,1] + A2*nz[j,2]  (column-broadcast)
// ---------------------------------------------------------------------------
__global__ void k_adj(const float* __restrict__ A0, const float* __restrict__ A1,
                      const float* __restrict__ A2, const float* __restrict__ nz,
                      float* __restrict__ adj) {
  int idx = blockIdx.x * 256 + threadIdx.x;
  int i = idx >> 10;
  int j4 = (idx & 1023) << 2;
  int base = i * N + j4;
  const float4 a0 = *(const float4*)&A0[base];
  const float4 a1 = *(const float4*)&A1[base];
  const float4 a2 = *(const float4*)&A2[base];
  const float4 n0 = *(const float4*)&nz[j4 * 3];
  const float4 n1 = *(const float4*)&nz[j4 * 3 + 4];
  const float4 n2 = *(const float4*)&nz[j4 * 3 + 8];
  float4 o;
  o.x = a0.x * n0.x + a1.x * n0.y + a2.x * n0.z;
  o.y = a0.y * n0.w + a1.y * n1.x + a2.y * n1.y;
  o.z = a0.z * n1.z + a1.z * n1.w + a2.z * n2.x;
  o.w = a0.w * n2.y + a1.w * n2.z + a2.w * n2.w;
  *(float4*)&adj[base] = o;
}

// ---------------------------------------------------------------------------
// k_wsplit: split-bf16 transposed weights (Wq/Wk/Wv + W1).
// ---------------------------------------------------------------------------
__global__ void k_wsplit(const float* __restrict__ Wq, const float* __restrict__ Wk,
                         const float* __restrict__ Wv, const float* __restrict__ W1,
                         u16* __restrict__ WThi, u16* __restrict__ WTlo,
                         u16* __restrict__ W1Thi, u16* __restrict__ W1Tlo) {
  int idx = blockIdx.x * 256 + threadIdx.x;
  if (idx < 49152) {
    int gm = idx >> 14;
    int rem = idx & 16383;
    int col = rem >> 7, k = rem & 127;
    const float* W = (gm == 0) ? Wq : (gm == 1) ? Wk : Wv;
    float v = W[k * NH + col];
    WThi[idx] = hi16(v);
    WTlo[idx] = hi16(v - hif(v));
  } else {
    int rem = idx - 49152;
    int col = rem >> 9, k = rem & 511;
    float v = W1[k * NH + col];
    W1Thi[rem] = hi16(v);
    W1Tlo[rem] = hi16(v - hif(v));
  }
}

// ---------------------------------------------------------------------------
// k_xw1m: xw1 = x @ W1 via split-bf16 MFMA (round-12-verified).
// ---------------------------------------------------------------------------
__global__ __launch_bounds__(256) void k_xw1m(
    const float* __restrict__ x,
    const u16* __restrict__ W1Thi, const u16* __restrict__ W1Tlo,
    u16* __restrict__ xw1Thi, u16* __restrict__ xw1Tlo) {
  __shared__ u16 Ah[64][128];
  __shared__ u16 Al[64][128];
  __shared__ u16 Vst[2][128 * 24];
  int i0 = blockIdx.x * 16;
  int tid = threadIdx.x;
  int w = tid >> 6, l = tid & 63, g = l >> 4, l15 = l & 15;
  {
    int r = tid >> 4, cb = (tid & 15) * 4;
#pragma unroll
    for (int q = 0; q < 4; ++q) {
      int c = cb + q;
      const float4 a0 = *(const float4*)&x[(size_t)(i0 + r) * NF + c * 8];
      const float4 a1 = *(const float4*)&x[(size_t)(i0 + r) * NF + c * 8 + 4];
      bf16x8 hi8, lo8;
      const float* p0 = (const float*)&a0;
      const float* p1 = (const float*)&a1;
#pragma unroll
      for (int e = 0; e < 4; ++e) {
        float v0 = p0[e], v1 = p1[e];
        hi8[e] = (short)hi16(v0); hi8[4 + e] = (short)hi16(v1);
        lo8[e] = (short)hi16(v0 - hif(v0));
        lo8[4 + e] = (short)hi16(v1 - hif(v1));
      }
      *(bf16x8*)&Ah[c][r * 8] = hi8;
      *(bf16x8*)&Al[c][r * 8] = lo8;
    }
  }
  __syncthreads();
  f32x4 acc[2];
  acc[0] = (f32x4){0.f, 0.f, 0.f, 0.f};
  acc[1] = (f32x4){0.f, 0.f, 0.f, 0.f};
#pragma unroll 4
  for (int kb = 0; kb < 16; ++kb) {
    const bf16x8 ah = *(const bf16x8*)&Ah[kb * 4 + g][l15 * 8];
    const bf16x8 al = *(const bf16x8*)&Al[kb * 4 + g][l15 * 8];
#pragma unroll
    for (int cti = 0; cti < 2; ++cti) {
      int col = (2 * w + cti) * 16 + l15;
      const bf16x8 bh = *(const bf16x8*)&W1Thi[col * NF + kb * 32 + 8 * g];
      const bf16x8 bl = *(const bf16x8*)&W1Tlo[col * NF + kb * 32 + 8 * g];
      acc[cti] = __builtin_amdgcn_mfma_f32_16x16x32_bf16(ah, bh, acc[cti], 0, 0, 0);
      acc[cti] = __builtin_amdgcn_mfma_f32_16x16x32_bf16(ah, bl, acc[cti], 0, 0, 0);
      acc[cti] = __builtin_amdgcn_mfma_f32_16x16x32_bf16(al, bh, acc[cti], 0, 0, 0);
    }
  }
#pragma unroll
  for (int cti = 0; cti < 2; ++cti) {
    int col = (2 * w + cti) * 16 + l15;
#pragma unroll
    for (int i = 0; i < 4; ++i) {
      float v = acc[cti][i];
      Vst[0][col * 24 + 4 * g + i] = hi16(v);
      Vst[1][col * 24 + 4 * g + i] = hi16(v - hif(v));
    }
  }
  __syncthreads();
  {
    int d = tid >> 1, half = tid & 1;
    bf16x8 vh = *(const bf16x8*)&Vst[0][d * 24 + half * 8];
    bf16x8 vl = *(const bf16x8*)&Vst[1][d * 24 + half * 8];
    *(bf16x8*)&xw1Thi[(size_t)d * N + i0 + half * 8] = vh;
    *(bf16x8*)&xw1Tlo[(size_t)d * N + i0 + half * 8] = vl;
  }
}

// ---------------------------------------------------------------------------
// glds16: async global -> LDS, 16B per lane.
// ---------------------------------------------------------------------------
__device__ __forceinline__ void glds16(const void* g, void* l) {
  __builtin_amdgcn_global_load_lds(
      (const __attribute__((address_space(1))) void*)g,
      (__attribute__((address_space(3))) void*)l, 16, 0, 0);
}

// ---------------------------------------------------------------------------
// k_h v7: hp_chunk = adj[:, chunk] @ xw1[chunk, :] via split-bf16 MFMA.
// (unchanged, round-13-verified)
// ---------------------------------------------------------------------------
__global__ __launch_bounds__(512) void k_h(const float* __restrict__ adj,
                                           const u16* __restrict__ xw1Thi,
                                           const u16* __restrict__ xw1Tlo,
                                           float* __restrict__ hp0,
                                           float* __restrict__ hp1,
                                           float* __restrict__ hp2,
                                           float* __restrict__ hp3) {
  __shared__ u16 Ah[8][520];
  __shared__ u16 Al[8][520];
  __shared__ u16 Bh[8][1024];
  __shared__ u16 Bl[8][1024];
  int kbase = blockIdx.x * 1024;
  int i0 = blockIdx.y * 64;
  float* hp = (blockIdx.x == 0) ? hp0 : (blockIdx.x == 1) ? hp1
            : (blockIdx.x == 2) ? hp2 : hp3;
  int tid = threadIdx.x;
  int w = tid >> 6, l = tid & 63, g = l >> 4, l15 = l & 15;
  int rt = w & 3, cg = w >> 2;
  int srow = tid >> 3, sseg = tid & 7;
  int bkk[4], bbuf[4], bcol[4];
#pragma unroll
  for (int q = 0; q < 4; ++q) {
    int idx = w * 4 + q;
    bbuf[q] = idx >> 4; bkk[q] = (idx >> 1) & 7;
    bcol[q] = (idx & 1) * 64 + l;
  }

  float4 av0 = *(const float4*)&adj[(size_t)(i0 + srow) * N + kbase + sseg * 8];
  float4 av1 = *(const float4*)&adj[(size_t)(i0 + srow) * N + kbase + sseg * 8 + 4];
  bf16x8 breg[4];
#pragma unroll
  for (int q = 0; q < 4; ++q) {
    const u16* src = bbuf[q] ? xw1Tlo : xw1Thi;
    breg[q] = *(const bf16x8*)&src[(size_t)bcol[q] * N + kbase + bkk[q] * 8];
  }

  f32x4 acc[4];
#pragma unroll
  for (int nt = 0; nt < 4; ++nt) acc[nt] = (f32x4){0.f, 0.f, 0.f, 0.f};

  for (int t = 0; t < 16; ++t) {
    asm volatile("s_waitcnt lgkmcnt(0)" ::: "memory");
    __builtin_amdgcn_s_barrier();
    {
      bf16x8 hi8, lo8;
      const float* a0p = (const float*)&av0;
      const float* a1p = (const float*)&av1;
#pragma unroll
      for (int e = 0; e < 4; ++e) {
        float v0 = a0p[e], v1 = a1p[e];
        hi8[e] = (short)hi16(v0);     hi8[4 + e] = (short)hi16(v1);
        lo8[e] = (short)hi16(v0 - hif(v0));
        lo8[4 + e] = (short)hi16(v1 - hif(v1));
      }
      *(bf16x8*)&Ah[sseg][srow * 8] = hi8;
      *(bf16x8*)&Al[sseg][srow * 8] = lo8;
    }
#pragma unroll
    for (int q = 0; q < 4; ++q) {
      u16* dst = bbuf[q] ? &Bl[bkk[q]][0] : &Bh[bkk[q]][0];
      *(bf16x8*)&dst[idxB(bcol[q])] = breg[q];
    }
    if (t < 15) {
      int k0n = kbase + (t + 1) * 64;
      av0 = *(const float4*)&adj[(size_t)(i0 + srow) * N + k0n + sseg * 8];
      av1 = *(const float4*)&adj[(size_t)(i0 + srow) * N + k0n + sseg * 8 + 4];
#pragma unroll
      for (int q = 0; q < 4; ++q) {
        const u16* src = bbuf[q] ? xw1Tlo : xw1Thi;
        breg[q] = *(const bf16x8*)&src[(size_t)bcol[q] * N + k0n + bkk[q] * 8];
      }
    }
    asm volatile("s_waitcnt lgkmcnt(0)" ::: "memory");
    __builtin_amdgcn_s_barrier();

#pragma unroll
    for (int kb = 0; kb < 2; ++kb) {
      const bf16x8 ah = *(const bf16x8*)&Ah[kb * 4 + g][(rt * 16 + l15) * 8];
      const bf16x8 al = *(const bf16x8*)&Al[kb * 4 + g][(rt * 16 + l15) * 8];
#pragma unroll
      for (int nt = 0; nt < 4; ++nt) {
        int col = cg * 64 + nt * 16 + l15;
        const bf16x8 bh = *(const bf16x8*)&Bh[kb * 4 + g][idxB(col)];
        const bf16x8 bl = *(const bf16x8*)&Bl[kb * 4 + g][idxB(col)];
        acc[nt] = __builtin_amdgcn_mfma_f32_16x16x32_bf16(ah, bh, acc[nt], 0, 0, 0);
        acc[nt] = __builtin_amdgcn_mfma_f32_16x16x32_bf16(ah, bl, acc[nt], 0, 0, 0);
        acc[nt] = __builtin_amdgcn_mfma_f32_16x16x32_bf16(al, bh, acc[nt], 0, 0, 0);
      }
    }
  }
#pragma unroll
  for (int nt = 0; nt < 4; ++nt)
#pragma unroll
    for (int i = 0; i < 4; ++i)
      hp[(size_t)(i0 + rt * 16 + 4 * g + i) * NH + cg * 64 + nt * 16 + l15] =
          acc[nt][i];
}

// ---------------------------------------------------------------------------
// k_hsum: h = relu(hp0+hp1+hp2+hp3+b1) -> split-bf16 Hhi/Hlo [n][128].
// ---------------------------------------------------------------------------
__global__ void k_hsum(const float* __restrict__ hp0, const float* __restrict__ hp1,
                       const float* __restrict__ hp2, const float* __restrict__ hp3,
                       const float* __restrict__ b1,
                       u16* __restrict__ Hhi, u16* __restrict__ Hlo) {
  int idx = blockIdx.x * 256 + threadIdx.x;
  int gi = idx * 4;
  const float4 v0 = *(const float4*)&hp0[gi];
  const float4 v1 = *(const float4*)&hp1[gi];
  const float4 v2 = *(const float4*)&hp2[gi];
  const float4 v3 = *(const float4*)&hp3[gi];
  const float4 bv = *(const float4*)&b1[gi & (NH - 1)];
  float h[4];
  h[0] = fmaxf(v0.x + v1.x + v2.x + v3.x + bv.x, 0.f);
  h[1] = fmaxf(v0.y + v1.y + v2.y + v3.y + bv.y, 0.f);
  h[2] = fmaxf(v0.z + v1.z + v2.z + v3.z + bv.z, 0.f);
  h[3] = fmaxf(v0.w + v1.w + v2.w + v3.w + bv.w, 0.f);
  u16x4 hi, lo;
#pragma unroll
  for (int e = 0; e < 4; ++e) {
    hi[e] = hi16(h[e]);
    lo[e] = hi16(h[e] - hif(h[e]));
  }
  *(u16x4*)&Hhi[gi] = hi;
  *(u16x4*)&Hlo[gi] = lo;
}

// ---------------------------------------------------------------------------
// k_qkv2: Q/K/V = H @ W{q,k,v} + b via split-bf16 MFMA (round-11-verified).
// ---------------------------------------------------------------------------
__global__ __launch_bounds__(256) void k_qkv2(
    const u16* __restrict__ Hhi, const u16* __restrict__ Hlo,
    const u16* __restrict__ WThi, const u16* __restrict__ WTlo,
    const float* __restrict__ bq, const float* __restrict__ bk,
    const float* __restrict__ bv,
    u16* __restrict__ Qhi, u16* __restrict__ Qlo,
    u16* __restrict__ Khi, u16* __restrict__ Klo,
    u16* __restrict__ VThi, u16* __restrict__ VTlo) {
  __shared__ u16 Vst[2][128 * 24];
  int i0 = blockIdx.x * 16;
  int tid = threadIdx.x;
  int w = tid >> 6, l = tid & 63, g = l >> 4, l15 = l & 15;
  bf16x8 ah[4], al[4];
#pragma unroll
  for (int kb = 0; kb < 4; ++kb) {
    ah[kb] = *(const bf16x8*)&Hhi[(i0 + l15) * NH + kb * 32 + 8 * g];
    al[kb] = *(const bf16x8*)&Hlo[(i0 + l15) * NH + kb * 32 + 8 * g];
  }
#pragma unroll
  for (int gm = 0; gm < 3; ++gm) {
    const u16* wth = WThi + gm * 16384;
    const u16* wtl = WTlo + gm * 16384;
    const float* bb = (gm == 0) ? bq : (gm == 1) ? bk : bv;
#pragma unroll
    for (int cti = 0; cti < 2; ++cti) {
      int ct = 2 * w + cti;
      int col = ct * 16 + l15;
      f32x4 acc = (f32x4){0.f, 0.f, 0.f, 0.f};
#pragma unroll
      for (int kb = 0; kb < 4; ++kb) {
        const bf16x8 bh = *(const bf16x8*)&wth[col * NH + kb * 32 + 8 * g];
        const bf16x8 bl = *(const bf16x8*)&wtl[col * NH + kb * 32 + 8 * g];
        acc = __builtin_amdgcn_mfma_f32_16x16x32_bf16(ah[kb], bh, acc, 0, 0, 0);
        acc = __builtin_amdgcn_mfma_f32_16x16x32_bf16(ah[kb], bl, acc, 0, 0, 0);
        acc = __builtin_amdgcn_mfma_f32_16x16x32_bf16(al[kb], bh, acc, 0, 0, 0);
      }
      float bias = bb[col];
#pragma unroll
      for (int i = 0; i < 4; ++i) {
        float v = acc[i] + bias;
        u16 vh = hi16(v), vl = hi16(v - hif(v));
        int row = i0 + 4 * g + i;
        if (gm == 0) {
          Qhi[row * NH + col] = vh; Qlo[row * NH + col] = vl;
        } else if (gm == 1) {
          Khi[row * NH + col] = vh; Klo[row * NH + col] = vl;
        } else {
          Vst[0][col * 24 + 4 * g + i] = vh;
          Vst[1][col * 24 + 4 * g + i] = vl;
        }
      }
    }
  }
  __syncthreads();
  {
    int d = tid >> 1, half = tid & 1;
    bf16x8 vh = *(const bf16x8*)&Vst[0][d * 24 + half * 8];
    bf16x8 vl = *(const bf16x8*)&Vst[1][d * 24 + half * 8];
    *(bf16x8*)&VThi[(size_t)d * N + i0 + half * 8] = vh;
    *(bf16x8*)&VTlo[(size_t)d * N + i0 + half * 8] = vl;
  }
}

// ---------------------------------------------------------------------------
// k_attn v7: split-bf16 MFMA flash attention.
// Grid (CSPLIT, 64): BM=64 rows/block, 256 threads (4 waves), LDS 80 KB ->
// 2 blocks/CU (cross-block phase overlap).  Wave w owns rows 16w..16w+15
// (same per-wave maps as verified v6).  adj mask double-buffered in regs:
// jt+1's loads issued before PV (T14), vmcnt-counted so K drains pre-QK
// (vmcnt(8)) and V drains pre-PV (vmcnt(16), adj in flight).
// ---------------------------------------------------------------------------
__global__ __launch_bounds__(256) void k_attn(
    const u16* __restrict__ Qhi, const u16* __restrict__ Qlo,
    const u16* __restrict__ Khi, const u16* __restrict__ Klo,
    const u16* __restrict__ VThi, const u16* __restrict__ VTlo,
    const float* __restrict__ adj,
    float* __restrict__ xp0, float* __restrict__ xp1, float* __restrict__ xp2,
    float* __restrict__ xp3, float* __restrict__ xp4, float* __restrict__ xp5,
    float* __restrict__ xp6, float* __restrict__ xp7,
    float* __restrict__ ml) {
  __shared__ u16 Ks[2][16][512];     // K^T chunk-planes (unchanged)
  __shared__ u16 Vs[2][8][1024];     // V chunk-planes (unchanged)
  __shared__ u16 Ps[2][8][512];      // P planes: 64 rows x 8
  int cid = blockIdx.x;
  int i0 = blockIdx.y * 64;
  int tid = threadIdx.x;
  int w = tid >> 6, l = tid & 63, g = l >> 4, l15 = l & 15;
  int ty = tid >> 4, tx16 = tid & 15;
  float* xp = (cid < 4) ? ((cid < 2) ? (cid == 0 ? xp0 : xp1) : (cid == 2 ? xp2 : xp3))
                        : ((cid < 6) ? (cid == 4 ? xp4 : xp5) : (cid == 6 ? xp6 : xp7));

  bf16x8 qh[4], ql[4];
  {
    const u16* qbh = &Qhi[(i0 + 16 * w + l15) * NH];
    const u16* qbl = &Qlo[(i0 + 16 * w + l15) * NH];
#pragma unroll
    for (int kb = 0; kb < 4; ++kb) {
      qh[kb] = *(const bf16x8*)&qbh[kb * 32 + 8 * g];
      ql[kb] = *(const bf16x8*)&qbl[kb * 32 + 8 * g];
    }
  }

  float m[4], li[4];
  f32x4 Xa[8];
#pragma unroll
  for (int i = 0; i < 4; ++i) { m[i] = -3.0e38f; li[i] = 0.f; }
#pragma unroll
  for (int nt = 0; nt < 8; ++nt) Xa[nt] = (f32x4){0.f, 0.f, 0.f, 0.f};

  // preload adj mask for jt=0
  float adjm[4][4];
  {
    int j0g = cid * (N / CSPLIT);
#pragma unroll
    for (int i = 0; i < 4; ++i)
#pragma unroll
      for (int ct = 0; ct < 4; ++ct)
        adjm[i][ct] = adj[(size_t)(i0 + 4 * ty + i) * N + j0g + ct * 16 + tx16];
  }

  for (int jt = 0; jt < 8; ++jt) {
    int j0g = cid * (N / CSPLIT) + jt * 64;
    asm volatile("s_waitcnt lgkmcnt(0)" ::: "memory");  // own prev PV LDS reads done
    __builtin_amdgcn_s_barrier();                       // all waves done w/ Ks,Vs
    // K chunk-planes: 32 glds, 8/wave
#pragma unroll
    for (int q = 0; q < 8; ++q) {
      int idx = w * 8 + q;
      int buf = idx >> 4, c = idx & 15;
      const u16* ks = buf ? Klo : Khi;
      glds16(&ks[(j0g + l) * NH + c * 8], &Ks[buf][c][0]);
    }
    // V chunk-planes: 32 glds, 8/wave
#pragma unroll
    for (int q = 0; q < 8; ++q) {
      int idx = w * 8 + q;
      int buf = idx >> 4, cj = (idx >> 1) & 7, h = idx & 1;
      const u16* vsrc = buf ? VTlo : VThi;
      glds16(&vsrc[(h * 64 + l) * N + j0g + cj * 8], &Vs[buf][cj][h * 512]);
    }
    asm volatile("s_waitcnt vmcnt(8)" ::: "memory");    // adj+K landed; V in flight
    __builtin_amdgcn_s_barrier();

    // ---- QK^T via MFMA ----
    f32x4 acc[4];
#pragma unroll
    for (int ct = 0; ct < 4; ++ct) acc[ct] = (f32x4){0.f, 0.f, 0.f, 0.f};
#pragma unroll
    for (int kb = 0; kb < 4; ++kb) {
#pragma unroll
      for (int ct = 0; ct < 4; ++ct) {
        const bf16x8 kh = *(const bf16x8*)&Ks[0][kb * 4 + g][(ct * 16 + l15) * 8];
        const bf16x8 kl = *(const bf16x8*)&Ks[1][kb * 4 + g][(ct * 16 + l15) * 8];
        acc[ct] = __builtin_amdgcn_mfma_f32_16x16x32_bf16(qh[kb], kh, acc[ct], 0, 0, 0);
        acc[ct] = __builtin_amdgcn_mfma_f32_16x16x32_bf16(qh[kb], kl, acc[ct], 0, 0, 0);
        acc[ct] = __builtin_amdgcn_mfma_f32_16x16x32_bf16(ql[kb], kh, acc[ct], 0, 0, 0);
      }
    }

    // ---- mask + online softmax; P (wave-private) to planes ----
#pragma unroll
    for (int i = 0; i < 4; ++i) {
      float p[4];
      float s0 = acc[0][i] * adjm[i][0];
      float s1 = acc[1][i] * adjm[i][1];
      float s2 = acc[2][i] * adjm[i][2];
      float s3 = acc[3][i] * adjm[i][3];
      float t = fmaxf(fmaxf(s0, s1), fmaxf(s2, s3));
      t = fmaxf(t, __shfl_xor(t, 1));
      t = fmaxf(t, __shfl_xor(t, 2));
      t = fmaxf(t, __shfl_xor(t, 4));
      t = fmaxf(t, __shfl_xor(t, 8));
      float mn = fmaxf(m[i], t);
      float sc = __expf(m[i] - mn);
      p[0] = __expf(s0 - mn); p[1] = __expf(s1 - mn);
      p[2] = __expf(s2 - mn); p[3] = __expf(s3 - mn);
      float ps = p[0] + p[1] + p[2] + p[3];
      ps += __shfl_xor(ps, 1);
      ps += __shfl_xor(ps, 2);
      ps += __shfl_xor(ps, 4);
      ps += __shfl_xor(ps, 8);
      li[i] = li[i] * sc + ps;
      m[i] = mn;
#pragma unroll
      for (int nt = 0; nt < 8; ++nt) Xa[nt][i] *= sc;
      int row = 4 * ty + i;
#pragma unroll
      for (int ct = 0; ct < 4; ++ct) {
        float pe = p[ct];
        float po = __shfl_xor(pe, 1);
        int cj = ct * 2 + (tx16 >> 3);
        int e = (ct * 16 + tx16) & 7;
        unsigned int hpk = (__float_as_uint(po) & 0xffff0000u)
                         | (__float_as_uint(pe) >> 16);
        float pel = pe - hif(pe), pol = po - hif(po);
        unsigned int lpk = (__float_as_uint(pol) & 0xffff0000u)
                         | (__float_as_uint(pel) >> 16);
        if (!(tx16 & 1)) {
          *(unsigned int*)&Ps[0][cj][row * 8 + e] = hpk;
          *(unsigned int*)&Ps[1][cj][row * 8 + e] = lpk;
        }
      }
    }
    asm volatile("s_waitcnt lgkmcnt(0)" ::: "memory");  // P writes + QK reads done
    // prefetch adj mask for jt+1 (flies under PV + next staging)
    if (jt < 7) {
      int j0n = j0g + 64;
#pragma unroll
      for (int i = 0; i < 4; ++i)
#pragma unroll
        for (int ct = 0; ct < 4; ++ct)
          adjm[i][ct] = adj[(size_t)(i0 + 4 * ty + i) * N + j0n + ct * 16 + tx16];
      asm volatile("s_waitcnt vmcnt(16)" ::: "memory"); // V drained; adj in flight
    } else {
      asm volatile("s_waitcnt vmcnt(0)" ::: "memory");
    }
    __builtin_amdgcn_s_barrier();                       // all waves: V staged

    // ---- PV via MFMA ----
#pragma unroll
    for (int jb = 0; jb < 2; ++jb) {
      const bf16x8 ph = *(const bf16x8*)&Ps[0][jb * 4 + g][(16 * w + l15) * 8];
      const bf16x8 pl = *(const bf16x8*)&Ps[1][jb * 4 + g][(16 * w + l15) * 8];
#pragma unroll
      for (int nt = 0; nt < 8; ++nt) {
        const bf16x8 vh = *(const bf16x8*)&Vs[0][jb * 4 + g][(nt * 16 + l15) * 8];
        const bf16x8 vl = *(const bf16x8*)&Vs[1][jb * 4 + g][(nt * 16 + l15) * 8];
        Xa[nt] = __builtin_amdgcn_mfma_f32_16x16x32_bf16(ph, vh, Xa[nt], 0, 0, 0);
        Xa[nt] = __builtin_amdgcn_mfma_f32_16x16x32_bf16(ph, vl, Xa[nt], 0, 0, 0);
        Xa[nt] = __builtin_amdgcn_mfma_f32_16x16x32_bf16(pl, vh, Xa[nt], 0, 0, 0);
      }
    }
  }

#pragma unroll
  for (int i = 0; i < 4; ++i) {
    int row = i0 + 4 * ty + i;
    float inv = 1.f / li[i];
#pragma unroll
    for (int nt = 0; nt < 8; ++nt)
      xp[row * NH + nt * 16 + tx16] = Xa[nt][i] * inv;
    if (tx16 == 0) {
      ml[(cid * N + row) * 2 + 0] = m[i];
      ml[(cid * N + row) * 2 + 1] = li[i];
    }
  }
}

// ---------------------------------------------------------------------------
// k_comb: merge 8 chunk-partials, normalize, relu -> Xt
// ---------------------------------------------------------------------------
__global__ void k_comb(const float* __restrict__ xp0, const float* __restrict__ xp1,
                       const float* __restrict__ xp2, const float* __restrict__ xp3,
                       const float* __restrict__ xp4, const float* __restrict__ xp5,
                       const float* __restrict__ xp6, const float* __restrict__ xp7,
                       const float* __restrict__ ml, float* __restrict__ Xt) {
  int idx = blockIdx.x * 256 + threadIdx.x;
  int r = idx >> 5, d4 = (idx & 31) << 2;
  float mm[8], ll[8];
#pragma unroll
  for (int c = 0; c < 8; ++c) {
    mm[c] = ml[(c * N + r) * 2 + 0];
    ll[c] = ml[(c * N + r) * 2 + 1];
  }
  float ms = mm[0];
#pragma unroll
  for (int c = 1; c < 8; ++c) ms = fmaxf(ms, mm[c]);
  float e[8], den = 0.f;
#pragma unroll
  for (int c = 0; c < 8; ++c) { e[c] = __expf(mm[c] - ms); den += e[c] * ll[c]; }
  float inv = 1.f / den;
  const float4 a0 = *(const float4*)&xp0[r * NH + d4];
  const float4 a1 = *(const float4*)&xp1[r * NH + d4];
  const float4 a2 = *(const float4*)&xp2[r * NH + d4];
  const float4 a3 = *(const float4*)&xp3[r * NH + d4];
  const float4 a4 = *(const float4*)&xp4[r * NH + d4];
  const float4 a5 = *(const float4*)&xp5[r * NH + d4];
  const float4 a6 = *(const float4*)&xp6[r * NH + d4];
  const float4 a7 = *(const float4*)&xp7[r * NH + d4];
  float4 o;
  o.x = a0.x * e[0] + a1.x * e[1] + a2.x * e[2] + a3.x * e[3]
      + a4.x * e[4] + a5.x * e[5] + a6.x * e[6] + a7.x * e[7];
  o.y = a0.y * e[0] + a1.y * e[1] + a2.y * e[2] + a3.y * e[3]
      + a4.y * e[4] + a5.y * e[5] + a6.y * e[6] + a7.y * e[7];
  o.z = a0.z * e[0] + a1.z * e[1] + a2.z * e[2] + a3.z * e[3]
      + a4.z * e[4] + a5.z * e[5] + a6.z * e[6] + a7.z * e[7];
  o.w = a0.w * e[0] + a1.w * e[1] + a2.w * e[2] + a3.w * e[3]
      + a4.w * e[4] + a5.w * e[5] + a6.w * e[6] + a7.w * e[7];
  o.x = fmaxf(o.x * inv, 0.f); o.y = fmaxf(o.y * inv, 0.f);
  o.z = fmaxf(o.z * inv, 0.f); o.w = fmaxf(o.w * inv, 0.f);
  *(float4*)&Xt[r * NH + d4] = o;
}

// ---------------------------------------------------------------------------
// k_xtw2: xtw2 = Xt @ W2.  16 rows/block, 256 blocks, 256 threads.
// ---------------------------------------------------------------------------
__global__ __launch_bounds__(256) void k_xtw2(const float* __restrict__ Xt,
                                              const float* __restrict__ W2,
                                              float* __restrict__ xtw2) {
  __shared__ float xs[16 * 132];
  __shared__ float w2s[NH * NC];
  int i0 = blockIdx.x * 16;
  int tid = threadIdx.x;
#pragma unroll
  for (int s = 0; s < 2; ++s) {
    int f4 = tid + 256 * s;
    int r = f4 >> 5, k4 = (f4 & 31) << 2;
    const float4 v = *(const float4*)&Xt[(i0 + r) * NH + k4];
    *(float4*)&xs[r * 132 + k4] = v;
    *(float4*)&w2s[f4 * 4] = *(const float4*)&W2[f4 * 4];
  }
  __syncthreads();
  int r = tid >> 4, c = tid & 15;
  float acc = 0.f;
#pragma unroll 8
  for (int k = 0; k < NH; ++k)
    acc += xs[r * 132 + k] * w2s[k * NC + c];
  xtw2[(i0 + r) * NC + c] = acc;
}

// ---------------------------------------------------------------------------
// k_z: z = adj @ xtw2 + b2; out = rowsoftmax(z).  BM=8, 512 blocks.
// ---------------------------------------------------------------------------
__global__ __launch_bounds__(256) void k_z(const float* __restrict__ adj,
                                           const float* __restrict__ xtw2,
                                           const float* __restrict__ b2,
                                           float* __restrict__ out) {
  __shared__ float xwsT[16 * 68];
  int i0 = blockIdx.x * 8;
  int tid = threadIdx.x;
  int ty = tid >> 6, cg = (tid >> 4) & 3, jg = tid & 15;
  int jr = tid >> 2, cq = tid & 3;
  float acc[2][4];
#pragma unroll
  for (int i = 0; i < 2; ++i)
#pragma unroll
    for (int c = 0; c < 4; ++c) acc[i][c] = 0.f;

  for (int j0 = 0; j0 < N; j0 += 64) {
    float4 av[2];
#pragma unroll
    for (int i = 0; i < 2; ++i)
      av[i] = *(const float4*)&adj[(i0 + 2 * ty + i) * N + j0 + 4 * jg];
    const float4 xv = *(const float4*)&xtw2[(j0 + jr) * NC + 4 * cq];
    __syncthreads();
    xwsT[(4 * cq + 0) * 68 + jr] = xv.x;
    xwsT[(4 * cq + 1) * 68 + jr] = xv.y;
    xwsT[(4 * cq + 2) * 68 + jr] = xv.z;
    xwsT[(4 * cq + 3) * 68 + jr] = xv.w;
    __syncthreads();
#pragma unroll
    for (int c = 0; c < 4; ++c) {
      const float4 wv = *(const float4*)&xwsT[(4 * cg + c) * 68 + 4 * jg];
#pragma unroll
      for (int i = 0; i < 2; ++i)
        acc[i][c] += av[i].x * wv.x + av[i].y * wv.y
                   + av[i].z * wv.z + av[i].w * wv.w;
    }
  }
#pragma unroll
  for (int i = 0; i < 2; ++i)
#pragma unroll
    for (int c = 0; c < 4; ++c) {
      float v = acc[i][c];
      v += __shfl_xor(v, 1);
      v += __shfl_xor(v, 2);
      v += __shfl_xor(v, 4);
      v += __shfl_xor(v, 8);
      acc[i][c] = v;
    }
  float bv0 = b2[4 * cg + 0], bv1 = b2[4 * cg + 1];
  float bv2 = b2[4 * cg + 2], bv3 = b2[4 * cg + 3];
#pragma unroll
  for (int i = 0; i < 2; ++i) {
    float z0 = acc[i][0] + bv0, z1 = acc[i][1] + bv1;
    float z2 = acc[i][2] + bv2, z3 = acc[i][3] + bv3;
    float mv = fmaxf(fmaxf(z0, z1), fmaxf(z2, z3));
    mv = fmaxf(mv, __shfl_xor(mv, 16));
    mv = fmaxf(mv, __shfl_xor(mv, 32));
    float e0 = __expf(z0 - mv), e1 = __expf(z1 - mv);
    float e2 = __expf(z2 - mv), e3 = __expf(z3 - mv);
    float s = e0 + e1 + e2 + e3;
    s += __shfl_xor(s, 16);
    s += __shfl_xor(s, 32);
    if (jg == 0) {
      float4 o = {e0 / s, e1 / s, e2 / s, e3 / s};
      *(float4*)&out[(i0 + 2 * ty + i) * NC + 4 * cg] = o;
    }
  }
}

// ---------------------------------------------------------------------------
extern "C" void kernel_launch(void* const* d_in, const int* in_sizes, int n_in,
                              void* d_out, int out_size, void* d_ws, size_t ws_size,
                              hipStream_t stream) {
  const float* A0  = (const float*)d_in[0];
  const float* A1  = (const float*)d_in[1];
  const float* A2  = (const float*)d_in[2];
  const float* x   = (const float*)d_in[3];
  const float* Wa1 = (const float*)d_in[4];  const float* ba1 = (const float*)d_in[5];
  const float* Wa2 = (const float*)d_in[6];  const float* ba2 = (const float*)d_in[7];
  const float* Wa3 = (const float*)d_in[8];  const float* ba3 = (const float*)d_in[9];
  const float* Wagg = (const float*)d_in[10]; const float* bagg = (const float*)d_in[11];
  const float* W1  = (const float*)d_in[12]; const float* b1  = (const float*)d_in[13];
  const float* Wq  = (const float*)d_in[14]; const float* bq  = (const float*)d_in[15];
  const float* Wk  = (const float*)d_in[16]; const float* bk  = (const float*)d_in[17];
  const float* Wv  = (const float*)d_in[18]; const float* bv  = (const float*)d_in[19];
  const float* W2  = (const float*)d_in[20]; const float* b2  = (const float*)d_in[21];

  float* out0 = (float*)d_out;            // [N,16] class softmax
  float* nz   = out0 + N * NC;            // [N,3] mixing weights (output 1)

  float* ws   = (float*)d_ws;
  float* adj  = ws;                       // N*N
  float* Wc2  = adj + (size_t)N * N;      // 3*N*4
  float* bz   = Wc2 + 3 * N * 4;          // 16
  float* xw1  = bz + 16;                  // N*NH region -> xw1T bf16 / attn xp0
  float* hpre = xw1 + N * NH;             // N*NH  (h partial 0 / attn xp1)
  float* QhT  = hpre + N * NH;            // N*NH region: zp | W1T planes | Qhi/Qlo
  float* KhT  = QhT + N * NH;             // N*NH region -> Khi/Klo bf16
  float* Vh   = KhT + N * NH;             // N*NH region -> VThi/VTlo bf16
  float* Xt   = Vh + N * NH;              // N*NH  (H planes, then attn xp7/Xt)
  float* xtw2 = Xt + N * NH;              // N*NC  (WT planes, then xtw2)
  float* P2   = xtw2 + N * NC;            // h partial 1 / attn xp2
  float* P3   = P2 + N * NH;              // h partial 2 / attn xp3
  float* P4   = P3 + N * NH;              // h partial 3 / attn xp4
  float* P5   = P4 + N * NH;
  float* P6   = P5 + N * NH;
  float* ml   = P6 + N * NH;              // 8*N*2
  float* zp   = QhT;                      // [N][12] f32 = 192 KB (head of QhT)

  u16* xw1Thi = (u16*)xw1; u16* xw1Tlo = xw1Thi + (size_t)N * NH;
  u16* Qhi  = (u16*)QhT; u16* Qlo = Qhi + (size_t)N * NH;
  u16* Khi  = (u16*)KhT; u16* Klo = Khi + (size_t)N * NH;
  u16* VThi = (u16*)Vh;  u16* VTlo = VThi + (size_t)N * NH;
  u16* Hhi  = (u16*)Xt;  u16* Hlo = Hhi + (size_t)N * NH;
  u16* WThi = (u16*)xtw2; u16* WTlo = WThi + (size_t)3 * NH * NH;
  u16* W1Thi = (u16*)(QhT + 65536); u16* W1Tlo = W1Thi + (size_t)NF * NH;

  hipLaunchKernelGGL(k_wc, dim3(48), dim3(256), 0, stream,
                     Wa1, Wa2, Wa3, Wagg, ba1, ba2, ba3, bagg, Wc2, bz);
  hipLaunchKernelGGL(k_wsplit, dim3(448), dim3(256), 0, stream,
                     Wq, Wk, Wv, W1, WThi, WTlo, W1Thi, W1Tlo);
  hipLaunchKernelGGL(k_z4p, dim3(N / 4), dim3(256), 0, stream,
                     A0, Wc2 + 0 * N * 4, zp + 0);
  hipLaunchKernelGGL(k_z4p, dim3(N / 4), dim3(256), 0, stream,
                     A1, Wc2 + 1 * N * 4, zp + 3);
  hipLaunchKernelGGL(k_z4p, dim3(N / 4), dim3(256), 0, stream,
                     A2, Wc2 + 2 * N * 4, zp + 6);
  hipLaunchKernelGGL(k_nz, dim3(N / 256), dim3(256), 0, stream, zp, bz, nz);
  hipLaunchKernelGGL(k_adj, dim3(N * N / 4 / 256), dim3(256), 0, stream,
                     A0, A1, A2, nz, adj);
  hipLaunchKernelGGL(k_xw1m, dim3(N / 16), dim3(256), 0, stream,
                     x, W1Thi, W1Tlo, xw1Thi, xw1Tlo);
  hipLaunchKernelGGL(k_h, dim3(4, N / 64), dim3(512), 0, stream,
                     adj, xw1Thi, xw1Tlo, hpre, P2, P3, P4);
  hipLaunchKernelGGL(k_hsum, dim3(N * NH / 4 / 256), dim3(256), 0, stream,
                     hpre, P2, P3, P4, b1, Hhi, Hlo);
  hipLaunchKernelGGL(k_qkv2, dim3(N / 16), dim3(256), 0, stream,
                     Hhi, Hlo, WThi, WTlo, bq, bk, bv,
                     Qhi, Qlo, Khi, Klo, VThi, VTlo);
  hipLaunchKernelGGL(k_attn, dim3(CSPLIT, N / 64), dim3(256), 0, stream,
                     Qhi, Qlo, Khi, Klo, VThi, VTlo, adj,
                     xw1, hpre, P2, P3, P4, P5, P6, Xt, ml);
  hipLaunchKernelGGL(k_comb, dim3(N * NH / 4 / 256), dim3(256), 0, stream,
                     xw1, hpre, P2, P3, P4, P5, P6, Xt, ml, Xt);
  hipLaunchKernelGGL(k_xtw2, dim3(N / 16), dim3(256), 0, stream, Xt, W2, xtw2);
  hipLaunchKernelGGL(k_z, dim3(N / 8), dim3(256), 0, stream, adj, xtw2, b2, out0);
}

// Round 15
// 271.119 us; speedup vs baseline: 1.0350x; 1.0350x over previous
//
#include <hip/hip_runtime.h>
#include <math.h>

#define N 4096
#define NF 512
#define NH 128
#define NC 16
#define CSPLIT 8

typedef unsigned short u16;
typedef __attribute__((ext_vector_type(4))) unsigned short u16x4;
typedef __attribute__((ext_vector_type(8))) short bf16x8;
typedef __attribute__((ext_vector_type(4))) float f32x4;

__device__ __forceinline__ u16 hi16(float v) {
  return (u16)(__float_as_uint(v) >> 16);
}
__device__ __forceinline__ float hif(float v) {
  return __uint_as_float(__float_as_uint(v) & 0xffff0000u);
}
// B-plane swizzled u16 index: byte = col*16 ^ ((col&0x38)<<1)
__device__ __forceinline__ int idxB(int col) {
  return (col * 8) ^ (col & 0x38);
}

// ---------------------------------------------------------------------------
// k_wc: Wc2[k][j][4] = {sum_t Wa_k[j,t]*Wagg[k*64+t, c]}  (float4-aligned)
// ---------------------------------------------------------------------------
__global__ void k_wc(const float* __restrict__ Wa1, const float* __restrict__ Wa2,
                     const float* __restrict__ Wa3, const float* __restrict__ Wagg,
                     const float* __restrict__ ba1, const float* __restrict__ ba2,
                     const float* __restrict__ ba3, const float* __restrict__ bagg,
                     float* __restrict__ Wc2, float* __restrict__ bz) {
  int idx = blockIdx.x * 256 + threadIdx.x;
  if (idx < 3 * N) {
    int k = idx >> 12;
    int j = idx & (N - 1);
    const float* Wa = (k == 0) ? Wa1 : (k == 1) ? Wa2 : Wa3;
    float a0 = 0.f, a1 = 0.f, a2 = 0.f;
    for (int t = 0; t < 64; ++t) {
      float w = Wa[j * 64 + t];
      const float* wg = Wagg + (k * 64 + t) * 3;
      a0 += w * wg[0]; a1 += w * wg[1]; a2 += w * wg[2];
    }
    float4 o = {a0, a1, a2, 0.f};
    *(float4*)&Wc2[(k * N + j) * 4] = o;
  }
  if (blockIdx.x == 0 && threadIdx.x < 3) {
    int c = threadIdx.x;
    float acc = bagg[c];
    for (int t = 0; t < 64; ++t) {
      acc += ba1[t] * Wagg[t * 3 + c]
           + ba2[t] * Wagg[(64 + t) * 3 + c]
           + ba3[t] * Wagg[(128 + t) * 3 + c];
    }
    bz[c] = acc;
  }
}

// ---------------------------------------------------------------------------
// k_z4p: one matrix's z4 partial.  Grid 1024 blocks x 256 threads.
// ---------------------------------------------------------------------------
__global__ __launch_bounds__(256) void k_z4p(const float* __restrict__ A,
                                             const float* __restrict__ Wck,
                                             float* __restrict__ zpk) {
  __shared__ float red[4][3][4];
  int r0 = blockIdx.x * 4;
  int tid = threadIdx.x;
  int lane = tid & 63, wv = tid >> 6;
  float acc[4][3];
#pragma unroll
  for (int r = 0; r < 4; ++r) { acc[r][0] = 0.f; acc[r][1] = 0.f; acc[r][2] = 0.f; }
#pragma unroll
  for (int s = 0; s < 4; ++s) {
    int j4 = s * 1024 + tid * 4;
    const float4 w0 = *(const float4*)&Wck[(j4 + 0) * 4];
    const float4 w1 = *(const float4*)&Wck[(j4 + 1) * 4];
    const float4 w2 = *(const float4*)&Wck[(j4 + 2) * 4];
    const float4 w3 = *(const float4*)&Wck[(j4 + 3) * 4];
#pragma unroll
    for (int r = 0; r < 4; ++r) {
      const float4 a = *(const float4*)&A[(size_t)(r0 + r) * N + j4];
      acc[r][0] += a.x * w0.x + a.y * w1.x + a.z * w2.x + a.w * w3.x;
      acc[r][1] += a.x * w0.y + a.y * w1.y + a.z * w2.y + a.w * w3.y;
      acc[r][2] += a.x * w0.z + a.y * w1.z + a.z * w2.z + a.w * w3.z;
    }
  }
#pragma unroll
  for (int r = 0; r < 4; ++r) {
#pragma unroll
    for (int c = 0; c < 3; ++c) {
      float v = acc[r][c];
      v += __shfl_xor(v, 1);
      v += __shfl_xor(v, 2);
      v += __shfl_xor(v, 4);
      v += __shfl_xor(v, 8);
      v += __shfl_xor(v, 16);
      v += __shfl_xor(v, 32);
      if (lane == 0) red[r][c][wv] = v;
    }
  }
  __syncthreads();
  if (tid < 12) {
    int r = tid / 3; int c = tid - 3 * r;
    zpk[(r0 + r) * 12 + c] =
        red[r][c][0] + red[r][c][1] + red[r][c][2] + red[r][c][3];
  }
}

// ---------------------------------------------------------------------------
// k_nz: z4 = sum of 3 matrix partials + bz; 3-way softmax -> nz
// ---------------------------------------------------------------------------
__global__ void k_nz(const float* __restrict__ zp, const float* __restrict__ bz,
                     float* __restrict__ nz) {
  int row = blockIdx.x * 256 + threadIdx.x;
  const float* p = zp + row * 12;
  float z0 = p[0] + p[3] + p[6] + bz[0];
  float z1 = p[1] + p[4] + p[7] + bz[1];
  float z2 = p[2] + p[5] + p[8] + bz[2];
  float m = fmaxf(z0, fmaxf(z1, z2));
  float e0 = __expf(z0 - m), e1 = __expf(z1 - m), e2 = __expf(z2 - m);
  float s = e0 + e1 + e2;
  float* o = nz + row * 3;
  o[0] = e0 / s; o[1] = e1 / s; o[2] = e2 / s;
}

// ---------------------------------------------------------------------------
// k_adj: adj[i,j] = A0*nz[j,0] + A1*nz[j,1] + A2*nz[j,2]  (column-broadcast)
// ---------------------------------------------------------------------------
__global__ void k_adj(const float* __restrict__ A0, const float* __restrict__ A1,
                      const float* __restrict__ A2, const float* __restrict__ nz,
                      float* __restrict__ adj) {
  int idx = blockIdx.x * 256 + threadIdx.x;
  int i = idx >> 10;
  int j4 = (idx & 1023) << 2;
  int base = i * N + j4;
  const float4 a0 = *(const float4*)&A0[base];
  const float4 a1 = *(const float4*)&A1[base];
  const float4 a2 = *(const float4*)&A2[base];
  const float4 n0 = *(const float4*)&nz[j4 * 3];
  const float4 n1 = *(const float4*)&nz[j4 * 3 + 4];
  const float4 n2 = *(const float4*)&nz[j4 * 3 + 8];
  float4 o;
  o.x = a0.x * n0.x + a1.x * n0.y + a2.x * n0.z;
  o.y = a0.y * n0.w + a1.y * n1.x + a2.y * n1.y;
  o.z = a0.z * n1.z + a1.z * n1.w + a2.z * n2.x;
  o.w = a0.w * n2.y + a1.w * n2.z + a2.w * n2.w;
  *(float4*)&adj[base] = o;
}

// ---------------------------------------------------------------------------
// k_wsplit: split-bf16 transposed weights (Wq/Wk/Wv + W1).
// ---------------------------------------------------------------------------
__global__ void k_wsplit(const float* __restrict__ Wq, const float* __restrict__ Wk,
                         const float* __restrict__ Wv, const float* __restrict__ W1,
                         u16* __restrict__ WThi, u16* __restrict__ WTlo,
                         u16* __restrict__ W1Thi, u16* __restrict__ W1Tlo) {
  int idx = blockIdx.x * 256 + threadIdx.x;
  if (idx < 49152) {
    int gm = idx >> 14;
    int rem = idx & 16383;
    int col = rem >> 7, k = rem & 127;
    const float* W = (gm == 0) ? Wq : (gm == 1) ? Wk : Wv;
    float v = W[k * NH + col];
    WThi[idx] = hi16(v);
    WTlo[idx] = hi16(v - hif(v));
  } else {
    int rem = idx - 49152;
    int col = rem >> 9, k = rem & 511;
    float v = W1[k * NH + col];
    W1Thi[rem] = hi16(v);
    W1Tlo[rem] = hi16(v - hif(v));
  }
}

// ---------------------------------------------------------------------------
// k_xw1m: xw1 = x @ W1 via split-bf16 MFMA (round-12-verified).
// ---------------------------------------------------------------------------
__global__ __launch_bounds__(256) void k_xw1m(
    const float* __restrict__ x,
    const u16* __restrict__ W1Thi, const u16* __restrict__ W1Tlo,
    u16* __restrict__ xw1Thi, u16* __restrict__ xw1Tlo) {
  __shared__ u16 Ah[64][128];
  __shared__ u16 Al[64][128];
  __shared__ u16 Vst[2][128 * 24];
  int i0 = blockIdx.x * 16;
  int tid = threadIdx.x;
  int w = tid >> 6, l = tid & 63, g = l >> 4, l15 = l & 15;
  {
    int r = tid >> 4, cb = (tid & 15) * 4;
#pragma unroll
    for (int q = 0; q < 4; ++q) {
      int c = cb + q;
      const float4 a0 = *(const float4*)&x[(size_t)(i0 + r) * NF + c * 8];
      const float4 a1 = *(const float4*)&x[(size_t)(i0 + r) * NF + c * 8 + 4];
      bf16x8 hi8, lo8;
      const float* p0 = (const float*)&a0;
      const float* p1 = (const float*)&a1;
#pragma unroll
      for (int e = 0; e < 4; ++e) {
        float v0 = p0[e], v1 = p1[e];
        hi8[e] = (short)hi16(v0); hi8[4 + e] = (short)hi16(v1);
        lo8[e] = (short)hi16(v0 - hif(v0));
        lo8[4 + e] = (short)hi16(v1 - hif(v1));
      }
      *(bf16x8*)&Ah[c][r * 8] = hi8;
      *(bf16x8*)&Al[c][r * 8] = lo8;
    }
  }
  __syncthreads();
  f32x4 acc[2];
  acc[0] = (f32x4){0.f, 0.f, 0.f, 0.f};
  acc[1] = (f32x4){0.f, 0.f, 0.f, 0.f};
#pragma unroll 4
  for (int kb = 0; kb < 16; ++kb) {
    const bf16x8 ah = *(const bf16x8*)&Ah[kb * 4 + g][l15 * 8];
    const bf16x8 al = *(const bf16x8*)&Al[kb * 4 + g][l15 * 8];
#pragma unroll
    for (int cti = 0; cti < 2; ++cti) {
      int col = (2 * w + cti) * 16 + l15;
      const bf16x8 bh = *(const bf16x8*)&W1Thi[col * NF + kb * 32 + 8 * g];
      const bf16x8 bl = *(const bf16x8*)&W1Tlo[col * NF + kb * 32 + 8 * g];
      acc[cti] = __builtin_amdgcn_mfma_f32_16x16x32_bf16(ah, bh, acc[cti], 0, 0, 0);
      acc[cti] = __builtin_amdgcn_mfma_f32_16x16x32_bf16(ah, bl, acc[cti], 0, 0, 0);
      acc[cti] = __builtin_amdgcn_mfma_f32_16x16x32_bf16(al, bh, acc[cti], 0, 0, 0);
    }
  }
#pragma unroll
  for (int cti = 0; cti < 2; ++cti) {
    int col = (2 * w + cti) * 16 + l15;
#pragma unroll
    for (int i = 0; i < 4; ++i) {
      float v = acc[cti][i];
      Vst[0][col * 24 + 4 * g + i] = hi16(v);
      Vst[1][col * 24 + 4 * g + i] = hi16(v - hif(v));
    }
  }
  __syncthreads();
  {
    int d = tid >> 1, half = tid & 1;
    bf16x8 vh = *(const bf16x8*)&Vst[0][d * 24 + half * 8];
    bf16x8 vl = *(const bf16x8*)&Vst[1][d * 24 + half * 8];
    *(bf16x8*)&xw1Thi[(size_t)d * N + i0 + half * 8] = vh;
    *(bf16x8*)&xw1Tlo[(size_t)d * N + i0 + half * 8] = vl;
  }
}

// ---------------------------------------------------------------------------
// glds16: async global -> LDS, 16B per lane.
// ---------------------------------------------------------------------------
__device__ __forceinline__ void glds16(const void* g, void* l) {
  __builtin_amdgcn_global_load_lds(
      (const __attribute__((address_space(1))) void*)g,
      (__attribute__((address_space(3))) void*)l, 16, 0, 0);
}

// ---------------------------------------------------------------------------
// k_h v7: hp_chunk = adj[:, chunk] @ xw1[chunk, :] via split-bf16 MFMA.
// (round-13-verified)
// ---------------------------------------------------------------------------
__global__ __launch_bounds__(512) void k_h(const float* __restrict__ adj,
                                           const u16* __restrict__ xw1Thi,
                                           const u16* __restrict__ xw1Tlo,
                                           float* __restrict__ hp0,
                                           float* __restrict__ hp1,
                                           float* __restrict__ hp2,
                                           float* __restrict__ hp3) {
  __shared__ u16 Ah[8][520];
  __shared__ u16 Al[8][520];
  __shared__ u16 Bh[8][1024];
  __shared__ u16 Bl[8][1024];
  int kbase = blockIdx.x * 1024;
  int i0 = blockIdx.y * 64;
  float* hp = (blockIdx.x == 0) ? hp0 : (blockIdx.x == 1) ? hp1
            : (blockIdx.x == 2) ? hp2 : hp3;
  int tid = threadIdx.x;
  int w = tid >> 6, l = tid & 63, g = l >> 4, l15 = l & 15;
  int rt = w & 3, cg = w >> 2;
  int srow = tid >> 3, sseg = tid & 7;
  int bkk[4], bbuf[4], bcol[4];
#pragma unroll
  for (int q = 0; q < 4; ++q) {
    int idx = w * 4 + q;
    bbuf[q] = idx >> 4; bkk[q] = (idx >> 1) & 7;
    bcol[q] = (idx & 1) * 64 + l;
  }

  float4 av0 = *(const float4*)&adj[(size_t)(i0 + srow) * N + kbase + sseg * 8];
  float4 av1 = *(const float4*)&adj[(size_t)(i0 + srow) * N + kbase + sseg * 8 + 4];
  bf16x8 breg[4];
#pragma unroll
  for (int q = 0; q < 4; ++q) {
    const u16* src = bbuf[q] ? xw1Tlo : xw1Thi;
    breg[q] = *(const bf16x8*)&src[(size_t)bcol[q] * N + kbase + bkk[q] * 8];
  }

  f32x4 acc[4];
#pragma unroll
  for (int nt = 0; nt < 4; ++nt) acc[nt] = (f32x4){0.f, 0.f, 0.f, 0.f};

  for (int t = 0; t < 16; ++t) {
    asm volatile("s_waitcnt lgkmcnt(0)" ::: "memory");
    __builtin_amdgcn_s_barrier();
    {
      bf16x8 hi8, lo8;
      const float* a0p = (const float*)&av0;
      const float* a1p = (const float*)&av1;
#pragma unroll
      for (int e = 0; e < 4; ++e) {
        float v0 = a0p[e], v1 = a1p[e];
        hi8[e] = (short)hi16(v0);     hi8[4 + e] = (short)hi16(v1);
        lo8[e] = (short)hi16(v0 - hif(v0));
        lo8[4 + e] = (short)hi16(v1 - hif(v1));
      }
      *(bf16x8*)&Ah[sseg][srow * 8] = hi8;
      *(bf16x8*)&Al[sseg][srow * 8] = lo8;
    }
#pragma unroll
    for (int q = 0; q < 4; ++q) {
      u16* dst = bbuf[q] ? &Bl[bkk[q]][0] : &Bh[bkk[q]][0];
      *(bf16x8*)&dst[idxB(bcol[q])] = breg[q];
    }
    if (t < 15) {
      int k0n = kbase + (t + 1) * 64;
      av0 = *(const float4*)&adj[(size_t)(i0 + srow) * N + k0n + sseg * 8];
      av1 = *(const float4*)&adj[(size_t)(i0 + srow) * N + k0n + sseg * 8 + 4];
#pragma unroll
      for (int q = 0; q < 4; ++q) {
        const u16* src = bbuf[q] ? xw1Tlo : xw1Thi;
        breg[q] = *(const bf16x8*)&src[(size_t)bcol[q] * N + k0n + bkk[q] * 8];
      }
    }
    asm volatile("s_waitcnt lgkmcnt(0)" ::: "memory");
    __builtin_amdgcn_s_barrier();

#pragma unroll
    for (int kb = 0; kb < 2; ++kb) {
      const bf16x8 ah = *(const bf16x8*)&Ah[kb * 4 + g][(rt * 16 + l15) * 8];
      const bf16x8 al = *(const bf16x8*)&Al[kb * 4 + g][(rt * 16 + l15) * 8];
#pragma unroll
      for (int nt = 0; nt < 4; ++nt) {
        int col = cg * 64 + nt * 16 + l15;
        const bf16x8 bh = *(const bf16x8*)&Bh[kb * 4 + g][idxB(col)];
        const bf16x8 bl = *(const bf16x8*)&Bl[kb * 4 + g][idxB(col)];
        acc[nt] = __builtin_amdgcn_mfma_f32_16x16x32_bf16(ah, bh, acc[nt], 0, 0, 0);
        acc[nt] = __builtin_amdgcn_mfma_f32_16x16x32_bf16(ah, bl, acc[nt], 0, 0, 0);
        acc[nt] = __builtin_amdgcn_mfma_f32_16x16x32_bf16(al, bh, acc[nt], 0, 0, 0);
      }
    }
  }
#pragma unroll
  for (int nt = 0; nt < 4; ++nt)
#pragma unroll
    for (int i = 0; i < 4; ++i)
      hp[(size_t)(i0 + rt * 16 + 4 * g + i) * NH + cg * 64 + nt * 16 + l15] =
          acc[nt][i];
}

// ---------------------------------------------------------------------------
// k_hsum: h = relu(hp0+hp1+hp2+hp3+b1) -> split-bf16 Hhi/Hlo [n][128].
// ---------------------------------------------------------------------------
__global__ void k_hsum(const float* __restrict__ hp0, const float* __restrict__ hp1,
                       const float* __restrict__ hp2, const float* __restrict__ hp3,
                       const float* __restrict__ b1,
                       u16* __restrict__ Hhi, u16* __restrict__ Hlo) {
  int idx = blockIdx.x * 256 + threadIdx.x;
  int gi = idx * 4;
  const float4 v0 = *(const float4*)&hp0[gi];
  const float4 v1 = *(const float4*)&hp1[gi];
  const float4 v2 = *(const float4*)&hp2[gi];
  const float4 v3 = *(const float4*)&hp3[gi];
  const float4 bv = *(const float4*)&b1[gi & (NH - 1)];
  float h[4];
  h[0] = fmaxf(v0.x + v1.x + v2.x + v3.x + bv.x, 0.f);
  h[1] = fmaxf(v0.y + v1.y + v2.y + v3.y + bv.y, 0.f);
  h[2] = fmaxf(v0.z + v1.z + v2.z + v3.z + bv.z, 0.f);
  h[3] = fmaxf(v0.w + v1.w + v2.w + v3.w + bv.w, 0.f);
  u16x4 hi, lo;
#pragma unroll
  for (int e = 0; e < 4; ++e) {
    hi[e] = hi16(h[e]);
    lo[e] = hi16(h[e] - hif(h[e]));
  }
  *(u16x4*)&Hhi[gi] = hi;
  *(u16x4*)&Hlo[gi] = lo;
}

// ---------------------------------------------------------------------------
// k_qkv2: Q/K/V = H @ W{q,k,v} + b via split-bf16 MFMA (round-11-verified).
// ---------------------------------------------------------------------------
__global__ __launch_bounds__(256) void k_qkv2(
    const u16* __restrict__ Hhi, const u16* __restrict__ Hlo,
    const u16* __restrict__ WThi, const u16* __restrict__ WTlo,
    const float* __restrict__ bq, const float* __restrict__ bk,
    const float* __restrict__ bv,
    u16* __restrict__ Qhi, u16* __restrict__ Qlo,
    u16* __restrict__ Khi, u16* __restrict__ Klo,
    u16* __restrict__ VThi, u16* __restrict__ VTlo) {
  __shared__ u16 Vst[2][128 * 24];
  int i0 = blockIdx.x * 16;
  int tid = threadIdx.x;
  int w = tid >> 6, l = tid & 63, g = l >> 4, l15 = l & 15;
  bf16x8 ah[4], al[4];
#pragma unroll
  for (int kb = 0; kb < 4; ++kb) {
    ah[kb] = *(const bf16x8*)&Hhi[(i0 + l15) * NH + kb * 32 + 8 * g];
    al[kb] = *(const bf16x8*)&Hlo[(i0 + l15) * NH + kb * 32 + 8 * g];
  }
#pragma unroll
  for (int gm = 0; gm < 3; ++gm) {
    const u16* wth = WThi + gm * 16384;
    const u16* wtl = WTlo + gm * 16384;
    const float* bb = (gm == 0) ? bq : (gm == 1) ? bk : bv;
#pragma unroll
    for (int cti = 0; cti < 2; ++cti) {
      int ct = 2 * w + cti;
      int col = ct * 16 + l15;
      f32x4 acc = (f32x4){0.f, 0.f, 0.f, 0.f};
#pragma unroll
      for (int kb = 0; kb < 4; ++kb) {
        const bf16x8 bh = *(const bf16x8*)&wth[col * NH + kb * 32 + 8 * g];
        const bf16x8 bl = *(const bf16x8*)&wtl[col * NH + kb * 32 + 8 * g];
        acc = __builtin_amdgcn_mfma_f32_16x16x32_bf16(ah[kb], bh, acc, 0, 0, 0);
        acc = __builtin_amdgcn_mfma_f32_16x16x32_bf16(ah[kb], bl, acc, 0, 0, 0);
        acc = __builtin_amdgcn_mfma_f32_16x16x32_bf16(al[kb], bh, acc, 0, 0, 0);
      }
      float bias = bb[col];
#pragma unroll
      for (int i = 0; i < 4; ++i) {
        float v = acc[i] + bias;
        u16 vh = hi16(v), vl = hi16(v - hif(v));
        int row = i0 + 4 * g + i;
        if (gm == 0) {
          Qhi[row * NH + col] = vh; Qlo[row * NH + col] = vl;
        } else if (gm == 1) {
          Khi[row * NH + col] = vh; Klo[row * NH + col] = vl;
        } else {
          Vst[0][col * 24 + 4 * g + i] = vh;
          Vst[1][col * 24 + 4 * g + i] = vl;
        }
      }
    }
  }
  __syncthreads();
  {
    int d = tid >> 1, half = tid & 1;
    bf16x8 vh = *(const bf16x8*)&Vst[0][d * 24 + half * 8];
    bf16x8 vl = *(const bf16x8*)&Vst[1][d * 24 + half * 8];
    *(bf16x8*)&VThi[(size_t)d * N + i0 + half * 8] = vh;
    *(bf16x8*)&VTlo[(size_t)d * N + i0 + half * 8] = vl;
  }
}

// ---------------------------------------------------------------------------
// k_attn v6: split-bf16 MFMA flash attention (round-13-verified, restored).
// Grid (CSPLIT, 32): BM=128 rows/block, 512 threads (8 waves), LDS 96 KB.
// ---------------------------------------------------------------------------
__global__ __launch_bounds__(512) void k_attn(
    const u16* __restrict__ Qhi, const u16* __restrict__ Qlo,
    const u16* __restrict__ Khi, const u16* __restrict__ Klo,
    const u16* __restrict__ VThi, const u16* __restrict__ VTlo,
    const float* __restrict__ adj,
    float* __restrict__ xp0, float* __restrict__ xp1, float* __restrict__ xp2,
    float* __restrict__ xp3, float* __restrict__ xp4, float* __restrict__ xp5,
    float* __restrict__ xp6, float* __restrict__ xp7,
    float* __restrict__ ml) {
  __shared__ u16 Ks[2][16][512];
  __shared__ u16 Vs[2][8][1024];
  __shared__ u16 Ps[2][8][1024];
  int cid = blockIdx.x;
  int i0 = blockIdx.y * 128;
  int tid = threadIdx.x;
  int w = tid >> 6, l = tid & 63, g = l >> 4, l15 = l & 15;
  int ty = tid >> 4, tx16 = tid & 15;
  float* xp = (cid < 4) ? ((cid < 2) ? (cid == 0 ? xp0 : xp1) : (cid == 2 ? xp2 : xp3))
                        : ((cid < 6) ? (cid == 4 ? xp4 : xp5) : (cid == 6 ? xp6 : xp7));

  bf16x8 qh[4], ql[4];
  {
    const u16* qbh = &Qhi[(i0 + 16 * w + l15) * NH];
    const u16* qbl = &Qlo[(i0 + 16 * w + l15) * NH];
#pragma unroll
    for (int kb = 0; kb < 4; ++kb) {
      qh[kb] = *(const bf16x8*)&qbh[kb * 32 + 8 * g];
      ql[kb] = *(const bf16x8*)&qbl[kb * 32 + 8 * g];
    }
  }

  float m[4], li[4];
  f32x4 Xa[8];
#pragma unroll
  for (int i = 0; i < 4; ++i) { m[i] = -3.0e38f; li[i] = 0.f; }
#pragma unroll
  for (int nt = 0; nt < 8; ++nt) Xa[nt] = (f32x4){0.f, 0.f, 0.f, 0.f};

  for (int jt = 0; jt < 8; ++jt) {
    int j0g = cid * (N / CSPLIT) + jt * 64;
    float adjm[4][4];
#pragma unroll
    for (int i = 0; i < 4; ++i)
#pragma unroll
      for (int ct = 0; ct < 4; ++ct)
        adjm[i][ct] = adj[(size_t)(i0 + 4 * ty + i) * N + j0g + ct * 16 + tx16];
    asm volatile("s_waitcnt lgkmcnt(0)" ::: "memory");
    __builtin_amdgcn_s_barrier();
#pragma unroll
    for (int q = 0; q < 4; ++q) {
      int idx = w * 4 + q;
      int buf = idx >> 4, c = idx & 15;
      const u16* ks = buf ? Klo : Khi;
      glds16(&ks[(j0g + l) * NH + c * 8], &Ks[buf][c][0]);
    }
#pragma unroll
    for (int q = 0; q < 4; ++q) {
      int idx = w * 4 + q;
      int buf = idx >> 4, cj = (idx >> 1) & 7, h = idx & 1;
      const u16* vsrc = buf ? VTlo : VThi;
      glds16(&vsrc[(h * 64 + l) * N + j0g + cj * 8], &Vs[buf][cj][h * 512]);
    }
    asm volatile("s_waitcnt vmcnt(4)" ::: "memory");
    __builtin_amdgcn_s_barrier();

    f32x4 acc[4];
#pragma unroll
    for (int ct = 0; ct < 4; ++ct) acc[ct] = (f32x4){0.f, 0.f, 0.f, 0.f};
#pragma unroll
    for (int kb = 0; kb < 4; ++kb) {
#pragma unroll
      for (int ct = 0; ct < 4; ++ct) {
        const bf16x8 kh = *(const bf16x8*)&Ks[0][kb * 4 + g][(ct * 16 + l15) * 8];
        const bf16x8 kl = *(const bf16x8*)&Ks[1][kb * 4 + g][(ct * 16 + l15) * 8];
        acc[ct] = __builtin_amdgcn_mfma_f32_16x16x32_bf16(qh[kb], kh, acc[ct], 0, 0, 0);
        acc[ct] = __builtin_amdgcn_mfma_f32_16x16x32_bf16(qh[kb], kl, acc[ct], 0, 0, 0);
        acc[ct] = __builtin_amdgcn_mfma_f32_16x16x32_bf16(ql[kb], kh, acc[ct], 0, 0, 0);
      }
    }

#pragma unroll
    for (int i = 0; i < 4; ++i) {
      float p[4];
      float s0 = acc[0][i] * adjm[i][0];
      float s1 = acc[1][i] * adjm[i][1];
      float s2 = acc[2][i] * adjm[i][2];
      float s3 = acc[3][i] * adjm[i][3];
      float t = fmaxf(fmaxf(s0, s1), fmaxf(s2, s3));
      t = fmaxf(t, __shfl_xor(t, 1));
      t = fmaxf(t, __shfl_xor(t, 2));
      t = fmaxf(t, __shfl_xor(t, 4));
      t = fmaxf(t, __shfl_xor(t, 8));
      float mn = fmaxf(m[i], t);
      float sc = __expf(m[i] - mn);
      p[0] = __expf(s0 - mn); p[1] = __expf(s1 - mn);
      p[2] = __expf(s2 - mn); p[3] = __expf(s3 - mn);
      float ps = p[0] + p[1] + p[2] + p[3];
      ps += __shfl_xor(ps, 1);
      ps += __shfl_xor(ps, 2);
      ps += __shfl_xor(ps, 4);
      ps += __shfl_xor(ps, 8);
      li[i] = li[i] * sc + ps;
      m[i] = mn;
#pragma unroll
      for (int nt = 0; nt < 8; ++nt) Xa[nt][i] *= sc;
      int row = 4 * ty + i;
#pragma unroll
      for (int ct = 0; ct < 4; ++ct) {
        float pe = p[ct];
        float po = __shfl_xor(pe, 1);
        int cj = ct * 2 + (tx16 >> 3);
        int e = (ct * 16 + tx16) & 7;
        unsigned int hpk = (__float_as_uint(po) & 0xffff0000u)
                         | (__float_as_uint(pe) >> 16);
        float pel = pe - hif(pe), pol = po - hif(po);
        unsigned int lpk = (__float_as_uint(pol) & 0xffff0000u)
                         | (__float_as_uint(pel) >> 16);
        if (!(tx16 & 1)) {
          *(unsigned int*)&Ps[0][cj][row * 8 + e] = hpk;
          *(unsigned int*)&Ps[1][cj][row * 8 + e] = lpk;
        }
      }
    }
    asm volatile("s_waitcnt vmcnt(0)" ::: "memory");
    __builtin_amdgcn_s_barrier();

#pragma unroll
    for (int jb = 0; jb < 2; ++jb) {
      const bf16x8 ph = *(const bf16x8*)&Ps[0][jb * 4 + g][(16 * w + l15) * 8];
      const bf16x8 pl = *(const bf16x8*)&Ps[1][jb * 4 + g][(16 * w + l15) * 8];
#pragma unroll
      for (int nt = 0; nt < 8; ++nt) {
        const bf16x8 vh = *(const bf16x8*)&Vs[0][jb * 4 + g][(nt * 16 + l15) * 8];
        const bf16x8 vl = *(const bf16x8*)&Vs[1][jb * 4 + g][(nt * 16 + l15) * 8];
        Xa[nt] = __builtin_amdgcn_mfma_f32_16x16x32_bf16(ph, vh, Xa[nt], 0, 0, 0);
        Xa[nt] = __builtin_amdgcn_mfma_f32_16x16x32_bf16(ph, vl, Xa[nt], 0, 0, 0);
        Xa[nt] = __builtin_amdgcn_mfma_f32_16x16x32_bf16(pl, vh, Xa[nt], 0, 0, 0);
      }
    }
  }

#pragma unroll
  for (int i = 0; i < 4; ++i) {
    int row = i0 + 4 * ty + i;
    float inv = 1.f / li[i];
#pragma unroll
    for (int nt = 0; nt < 8; ++nt)
      xp[row * NH + nt * 16 + tx16] = Xa[nt][i] * inv;
    if (tx16 == 0) {
      ml[(cid * N + row) * 2 + 0] = m[i];
      ml[(cid * N + row) * 2 + 1] = li[i];
    }
  }
}

// ---------------------------------------------------------------------------
// k_comb: merge 8 chunk-partials, normalize, relu -> Xt
// ---------------------------------------------------------------------------
__global__ void k_comb(const float* __restrict__ xp0, const float* __restrict__ xp1,
                       const float* __restrict__ xp2, const float* __restrict__ xp3,
                       const float* __restrict__ xp4, const float* __restrict__ xp5,
                       const float* __restrict__ xp6, const float* __restrict__ xp7,
                       const float* __restrict__ ml, float* __restrict__ Xt) {
  int idx = blockIdx.x * 256 + threadIdx.x;
  int r = idx >> 5, d4 = (idx & 31) << 2;
  float mm[8], ll[8];
#pragma unroll
  for (int c = 0; c < 8; ++c) {
    mm[c] = ml[(c * N + r) * 2 + 0];
    ll[c] = ml[(c * N + r) * 2 + 1];
  }
  float ms = mm[0];
#pragma unroll
  for (int c = 1; c < 8; ++c) ms = fmaxf(ms, mm[c]);
  float e[8], den = 0.f;
#pragma unroll
  for (int c = 0; c < 8; ++c) { e[c] = __expf(mm[c] - ms); den += e[c] * ll[c]; }
  float inv = 1.f / den;
  const float4 a0 = *(const float4*)&xp0[r * NH + d4];
  const float4 a1 = *(const float4*)&xp1[r * NH + d4];
  const float4 a2 = *(const float4*)&xp2[r * NH + d4];
  const float4 a3 = *(const float4*)&xp3[r * NH + d4];
  const float4 a4 = *(const float4*)&xp4[r * NH + d4];
  const float4 a5 = *(const float4*)&xp5[r * NH + d4];
  const float4 a6 = *(const float4*)&xp6[r * NH + d4];
  const float4 a7 = *(const float4*)&xp7[r * NH + d4];
  float4 o;
  o.x = a0.x * e[0] + a1.x * e[1] + a2.x * e[2] + a3.x * e[3]
      + a4.x * e[4] + a5.x * e[5] + a6.x * e[6] + a7.x * e[7];
  o.y = a0.y * e[0] + a1.y * e[1] + a2.y * e[2] + a3.y * e[3]
      + a4.y * e[4] + a5.y * e[5] + a6.y * e[6] + a7.y * e[7];
  o.z = a0.z * e[0] + a1.z * e[1] + a2.z * e[2] + a3.z * e[3]
      + a4.z * e[4] + a5.z * e[5] + a6.z * e[6] + a7.z * e[7];
  o.w = a0.w * e[0] + a1.w * e[1] + a2.w * e[2] + a3.w * e[3]
      + a4.w * e[4] + a5.w * e[5] + a6.w * e[6] + a7.w * e[7];
  o.x = fmaxf(o.x * inv, 0.f); o.y = fmaxf(o.y * inv, 0.f);
  o.z = fmaxf(o.z * inv, 0.f); o.w = fmaxf(o.w * inv, 0.f);
  *(float4*)&Xt[r * NH + d4] = o;
}

// ---------------------------------------------------------------------------
// k_xtw2: xtw2 = Xt @ W2.  16 rows/block, 256 blocks, 256 threads.
// ---------------------------------------------------------------------------
__global__ __launch_bounds__(256) void k_xtw2(const float* __restrict__ Xt,
                                              const float* __restrict__ W2,
                                              float* __restrict__ xtw2) {
  __shared__ float xs[16 * 132];
  __shared__ float w2s[NH * NC];
  int i0 = blockIdx.x * 16;
  int tid = threadIdx.x;
#pragma unroll
  for (int s = 0; s < 2; ++s) {
    int f4 = tid + 256 * s;
    int r = f4 >> 5, k4 = (f4 & 31) << 2;
    const float4 v = *(const float4*)&Xt[(i0 + r) * NH + k4];
    *(float4*)&xs[r * 132 + k4] = v;
    *(float4*)&w2s[f4 * 4] = *(const float4*)&W2[f4 * 4];
  }
  __syncthreads();
  int r = tid >> 4, c = tid & 15;
  float acc = 0.f;
#pragma unroll 8
  for (int k = 0; k < NH; ++k)
    acc += xs[r * 132 + k] * w2s[k * NC + c];
  xtw2[(i0 + r) * NC + c] = acc;
}

// ---------------------------------------------------------------------------
// k_z: z = adj @ xtw2 + b2; out = rowsoftmax(z).  BM=8, 512 blocks.
// ---------------------------------------------------------------------------
__global__ __launch_bounds__(256) void k_z(const float* __restrict__ adj,
                                           const float* __restrict__ xtw2,
                                           const float* __restrict__ b2,
                                           float* __restrict__ out) {
  __shared__ float xwsT[16 * 68];
  int i0 = blockIdx.x * 8;
  int tid = threadIdx.x;
  int ty = tid >> 6, cg = (tid >> 4) & 3, jg = tid & 15;
  int jr = tid >> 2, cq = tid & 3;
  float acc[2][4];
#pragma unroll
  for (int i = 0; i < 2; ++i)
#pragma unroll
    for (int c = 0; c < 4; ++c) acc[i][c] = 0.f;

  for (int j0 = 0; j0 < N; j0 += 64) {
    float4 av[2];
#pragma unroll
    for (int i = 0; i < 2; ++i)
      av[i] = *(const float4*)&adj[(i0 + 2 * ty + i) * N + j0 + 4 * jg];
    const float4 xv = *(const float4*)&xtw2[(j0 + jr) * NC + 4 * cq];
    __syncthreads();
    xwsT[(4 * cq + 0) * 68 + jr] = xv.x;
    xwsT[(4 * cq + 1) * 68 + jr] = xv.y;
    xwsT[(4 * cq + 2) * 68 + jr] = xv.z;
    xwsT[(4 * cq + 3) * 68 + jr] = xv.w;
    __syncthreads();
#pragma unroll
    for (int c = 0; c < 4; ++c) {
      const float4 wv = *(const float4*)&xwsT[(4 * cg + c) * 68 + 4 * jg];
#pragma unroll
      for (int i = 0; i < 2; ++i)
        acc[i][c] += av[i].x * wv.x + av[i].y * wv.y
                   + av[i].z * wv.z + av[i].w * wv.w;
    }
  }
#pragma unroll
  for (int i = 0; i < 2; ++i)
#pragma unroll
    for (int c = 0; c < 4; ++c) {
      float v = acc[i][c];
      v += __shfl_xor(v, 1);
      v += __shfl_xor(v, 2);
      v += __shfl_xor(v, 4);
      v += __shfl_xor(v, 8);
      acc[i][c] = v;
    }
  float bv0 = b2[4 * cg + 0], bv1 = b2[4 * cg + 1];
  float bv2 = b2[4 * cg + 2], bv3 = b2[4 * cg + 3];
#pragma unroll
  for (int i = 0; i < 2; ++i) {
    float z0 = acc[i][0] + bv0, z1 = acc[i][1] + bv1;
    float z2 = acc[i][2] + bv2, z3 = acc[i][3] + bv3;
    float mv = fmaxf(fmaxf(z0, z1), fmaxf(z2, z3));
    mv = fmaxf(mv, __shfl_xor(mv, 16));
    mv = fmaxf(mv, __shfl_xor(mv, 32));
    float e0 = __expf(z0 - mv), e1 = __expf(z1 - mv);
    float e2 = __expf(z2 - mv), e3 = __expf(z3 - mv);
    float s = e0 + e1 + e2 + e3;
    s += __shfl_xor(s, 16);
    s += __shfl_xor(s, 32);
    if (jg == 0) {
      float4 o = {e0 / s, e1 / s, e2 / s, e3 / s};
      *(float4*)&out[(i0 + 2 * ty + i) * NC + 4 * cg] = o;
    }
  }
}

// ---------------------------------------------------------------------------
extern "C" void kernel_launch(void* const* d_in, const int* in_sizes, int n_in,
                              void* d_out, int out_size, void* d_ws, size_t ws_size,
                              hipStream_t stream) {
  const float* A0  = (const float*)d_in[0];
  const float* A1  = (const float*)d_in[1];
  const float* A2  = (const float*)d_in[2];
  const float* x   = (const float*)d_in[3];
  const float* Wa1 = (const float*)d_in[4];  const float* ba1 = (const float*)d_in[5];
  const float* Wa2 = (const float*)d_in[6];  const float* ba2 = (const float*)d_in[7];
  const float* Wa3 = (const float*)d_in[8];  const float* ba3 = (const float*)d_in[9];
  const float* Wagg = (const float*)d_in[10]; const float* bagg = (const float*)d_in[11];
  const float* W1  = (const float*)d_in[12]; const float* b1  = (const float*)d_in[13];
  const float* Wq  = (const float*)d_in[14]; const float* bq  = (const float*)d_in[15];
  const float* Wk  = (const float*)d_in[16]; const float* bk  = (const float*)d_in[17];
  const float* Wv  = (const float*)d_in[18]; const float* bv  = (const float*)d_in[19];
  const float* W2  = (const float*)d_in[20]; const float* b2  = (const float*)d_in[21];

  float* out0 = (float*)d_out;            // [N,16] class softmax
  float* nz   = out0 + N * NC;            // [N,3] mixing weights (output 1)

  float* ws   = (float*)d_ws;
  float* adj  = ws;                       // N*N
  float* Wc2  = adj + (size_t)N * N;      // 3*N*4
  float* bz   = Wc2 + 3 * N * 4;          // 16
  float* xw1  = bz + 16;                  // N*NH region -> xw1T bf16 / attn xp0
  float* hpre = xw1 + N * NH;             // N*NH  (h partial 0 / attn xp1)
  float* QhT  = hpre + N * NH;            // N*NH region: zp | W1T planes | Qhi/Qlo
  float* KhT  = QhT + N * NH;             // N*NH region -> Khi/Klo bf16
  float* Vh   = KhT + N * NH;             // N*NH region -> VThi/VTlo bf16
  float* Xt   = Vh + N * NH;              // N*NH  (H planes, then attn xp7/Xt)
  float* xtw2 = Xt + N * NH;              // N*NC  (WT planes, then xtw2)
  float* P2   = xtw2 + N * NC;            // h partial 1 / attn xp2
  float* P3   = P2 + N * NH;              // h partial 2 / attn xp3
  float* P4   = P3 + N * NH;              // h partial 3 / attn xp4
  float* P5   = P4 + N * NH;
  float* P6   = P5 + N * NH;
  float* ml   = P6 + N * NH;              // 8*N*2
  float* zp   = QhT;                      // [N][12] f32 = 192 KB (head of QhT)

  u16* xw1Thi = (u16*)xw1; u16* xw1Tlo = xw1Thi + (size_t)N * NH;
  u16* Qhi  = (u16*)QhT; u16* Qlo = Qhi + (size_t)N * NH;
  u16* Khi  = (u16*)KhT; u16* Klo = Khi + (size_t)N * NH;
  u16* VThi = (u16*)Vh;  u16* VTlo = VThi + (size_t)N * NH;
  u16* Hhi  = (u16*)Xt;  u16* Hlo = Hhi + (size_t)N * NH;
  u16* WThi = (u16*)xtw2; u16* WTlo = WThi + (size_t)3 * NH * NH;
  u16* W1Thi = (u16*)(QhT + 65536); u16* W1Tlo = W1Thi + (size_t)NF * NH;

  hipLaunchKernelGGL(k_wc, dim3(48), dim3(256), 0, stream,
                     Wa1, Wa2, Wa3, Wagg, ba1, ba2, ba3, bagg, Wc2, bz);
  hipLaunchKernelGGL(k_wsplit, dim3(448), dim3(256), 0, stream,
                     Wq, Wk, Wv, W1, WThi, WTlo, W1Thi, W1Tlo);
  hipLaunchKernelGGL(k_z4p, dim3(N / 4), dim3(256), 0, stream,
                     A0, Wc2 + 0 * N * 4, zp + 0);
  hipLaunchKernelGGL(k_z4p, dim3(N / 4), dim3(256), 0, stream,
                     A1, Wc2 + 1 * N * 4, zp + 3);
  hipLaunchKernelGGL(k_z4p, dim3(N / 4), dim3(256), 0, stream,
                     A2, Wc2 + 2 * N * 4, zp + 6);
  hipLaunchKernelGGL(k_nz, dim3(N / 256), dim3(256), 0, stream, zp, bz, nz);
  hipLaunchKernelGGL(k_adj, dim3(N * N / 4 / 256), dim3(256), 0, stream,
                     A0, A1, A2, nz, adj);
  hipLaunchKernelGGL(k_xw1m, dim3(N / 16), dim3(256), 0, stream,
                     x, W1Thi, W1Tlo, xw1Thi, xw1Tlo);
  hipLaunchKernelGGL(k_h, dim3(4, N / 64), dim3(512), 0, stream,
                     adj, xw1Thi, xw1Tlo, hpre, P2, P3, P4);
  hipLaunchKernelGGL(k_hsum, dim3(N * NH / 4 / 256), dim3(256), 0, stream,
                     hpre, P2, P3, P4, b1, Hhi, Hlo);
  hipLaunchKernelGGL(k_qkv2, dim3(N / 16), dim3(256), 0, stream,
                     Hhi, Hlo, WThi, WTlo, bq, bk, bv,
                     Qhi, Qlo, Khi, Klo, VThi, VTlo);
  hipLaunchKernelGGL(k_attn, dim3(CSPLIT, N / 128), dim3(512), 0, stream,
                     Qhi, Qlo, Khi, Klo, VThi, VTlo, adj,
                     xw1, hpre, P2, P3, P4, P5, P6, Xt, ml);
  hipLaunchKernelGGL(k_comb, dim3(N * NH / 4 / 256), dim3(256), 0, stream,
                     xw1, hpre, P2, P3, P4, P5, P6, Xt, ml, Xt);
  hipLaunchKernelGGL(k_xtw2, dim3(N / 16), dim3(256), 0, stream, Xt, W2, xtw2);
  hipLaunchKernelGGL(k_z, dim3(N / 8), dim3(256), 0, stream, adj, xtw2, b2, out0);
}

// Round 16
// 260.353 us; speedup vs baseline: 1.0778x; 1.0414x over previous
//
#include <hip/hip_runtime.h>
#include <math.h>

#define N 4096
#define NF 512
#define NH 128
#define NC 16
#define CSPLIT 8

typedef unsigned short u16;
typedef __attribute__((ext_vector_type(4))) unsigned short u16x4;
typedef __attribute__((ext_vector_type(8))) short bf16x8;
typedef __attribute__((ext_vector_type(4))) float f32x4;

__device__ __forceinline__ u16 hi16(float v) {
  return (u16)(__float_as_uint(v) >> 16);
}
__device__ __forceinline__ float hif(float v) {
  return __uint_as_float(__float_as_uint(v) & 0xffff0000u);
}
// B-plane swizzled u16 index: byte = col*16 ^ ((col&0x38)<<1)
__device__ __forceinline__ int idxB(int col) {
  return (col * 8) ^ (col & 0x38);
}

// ---------------------------------------------------------------------------
// k_wc: Wc2[k][j][4] = {sum_t Wa_k[j,t]*Wagg[k*64+t, c]}  (float4-aligned)
// ---------------------------------------------------------------------------
__global__ void k_wc(const float* __restrict__ Wa1, const float* __restrict__ Wa2,
                     const float* __restrict__ Wa3, const float* __restrict__ Wagg,
                     const float* __restrict__ ba1, const float* __restrict__ ba2,
                     const float* __restrict__ ba3, const float* __restrict__ bagg,
                     float* __restrict__ Wc2, float* __restrict__ bz) {
  int idx = blockIdx.x * 256 + threadIdx.x;
  if (idx < 3 * N) {
    int k = idx >> 12;
    int j = idx & (N - 1);
    const float* Wa = (k == 0) ? Wa1 : (k == 1) ? Wa2 : Wa3;
    float a0 = 0.f, a1 = 0.f, a2 = 0.f;
    for (int t = 0; t < 64; ++t) {
      float w = Wa[j * 64 + t];
      const float* wg = Wagg + (k * 64 + t) * 3;
      a0 += w * wg[0]; a1 += w * wg[1]; a2 += w * wg[2];
    }
    float4 o = {a0, a1, a2, 0.f};
    *(float4*)&Wc2[(k * N + j) * 4] = o;
  }
  if (blockIdx.x == 0 && threadIdx.x < 3) {
    int c = threadIdx.x;
    float acc = bagg[c];
    for (int t = 0; t < 64; ++t) {
      acc += ba1[t] * Wagg[t * 3 + c]
           + ba2[t] * Wagg[(64 + t) * 3 + c]
           + ba3[t] * Wagg[(128 + t) * 3 + c];
    }
    bz[c] = acc;
  }
}

// ---------------------------------------------------------------------------
// k_z4p: z4 partials for all 3 matrices.  Grid (1024, 3), 256 threads.
// blockIdx.y selects matrix; block = 4 contiguous rows (linear stream).
// ---------------------------------------------------------------------------
__global__ __launch_bounds__(256) void k_z4p(const float* __restrict__ A0,
                                             const float* __restrict__ A1,
                                             const float* __restrict__ A2,
                                             const float* __restrict__ Wc2,
                                             float* __restrict__ zp) {
  __shared__ float red[4][3][4];
  const float* A = (blockIdx.y == 0) ? A0 : (blockIdx.y == 1) ? A1 : A2;
  const float* Wck = Wc2 + (size_t)blockIdx.y * N * 4;
  float* zpk = zp + blockIdx.y * 3;
  int r0 = blockIdx.x * 4;
  int tid = threadIdx.x;
  int lane = tid & 63, wv = tid >> 6;
  float acc[4][3];
#pragma unroll
  for (int r = 0; r < 4; ++r) { acc[r][0] = 0.f; acc[r][1] = 0.f; acc[r][2] = 0.f; }
#pragma unroll
  for (int s = 0; s < 4; ++s) {
    int j4 = s * 1024 + tid * 4;
    const float4 w0 = *(const float4*)&Wck[(j4 + 0) * 4];
    const float4 w1 = *(const float4*)&Wck[(j4 + 1) * 4];
    const float4 w2 = *(const float4*)&Wck[(j4 + 2) * 4];
    const float4 w3 = *(const float4*)&Wck[(j4 + 3) * 4];
#pragma unroll
    for (int r = 0; r < 4; ++r) {
      const float4 a = *(const float4*)&A[(size_t)(r0 + r) * N + j4];
      acc[r][0] += a.x * w0.x + a.y * w1.x + a.z * w2.x + a.w * w3.x;
      acc[r][1] += a.x * w0.y + a.y * w1.y + a.z * w2.y + a.w * w3.y;
      acc[r][2] += a.x * w0.z + a.y * w1.z + a.z * w2.z + a.w * w3.z;
    }
  }
#pragma unroll
  for (int r = 0; r < 4; ++r) {
#pragma unroll
    for (int c = 0; c < 3; ++c) {
      float v = acc[r][c];
      v += __shfl_xor(v, 1);
      v += __shfl_xor(v, 2);
      v += __shfl_xor(v, 4);
      v += __shfl_xor(v, 8);
      v += __shfl_xor(v, 16);
      v += __shfl_xor(v, 32);
      if (lane == 0) red[r][c][wv] = v;
    }
  }
  __syncthreads();
  if (tid < 12) {
    int r = tid / 3; int c = tid - 3 * r;
    zpk[(r0 + r) * 12 + c] =
        red[r][c][0] + red[r][c][1] + red[r][c][2] + red[r][c][3];
  }
}

// ---------------------------------------------------------------------------
// k_nz: z4 = sum of 3 matrix partials + bz; 3-way softmax -> nz
// ---------------------------------------------------------------------------
__global__ void k_nz(const float* __restrict__ zp, const float* __restrict__ bz,
                     float* __restrict__ nz) {
  int row = blockIdx.x * 256 + threadIdx.x;
  const float* p = zp + row * 12;
  float z0 = p[0] + p[3] + p[6] + bz[0];
  float z1 = p[1] + p[4] + p[7] + bz[1];
  float z2 = p[2] + p[5] + p[8] + bz[2];
  float m = fmaxf(z0, fmaxf(z1, z2));
  float e0 = __expf(z0 - m), e1 = __expf(z1 - m), e2 = __expf(z2 - m);
  float s = e0 + e1 + e2;
  float* o = nz + row * 3;
  o[0] = e0 / s; o[1] = e1 / s; o[2] = e2 / s;
}

// ---------------------------------------------------------------------------
// k_adj: adj[i,j] = A0*nz[j,0] + A1*nz[j,1] + A2*nz[j,2]  (column-broadcast)
// ---------------------------------------------------------------------------
__global__ void k_adj(const float* __restrict__ A0, const float* __restrict__ A1,
                      const float* __restrict__ A2, const float* __restrict__ nz,
                      float* __restrict__ adj) {
  int idx = blockIdx.x * 256 + threadIdx.x;
  int i = idx >> 10;
  int j4 = (idx & 1023) << 2;
  int base = i * N + j4;
  const float4 a0 = *(const float4*)&A0[base];
  const float4 a1 = *(const float4*)&A1[base];
  const float4 a2 = *(const float4*)&A2[base];
  const float4 n0 = *(const float4*)&nz[j4 * 3];
  const float4 n1 = *(const float4*)&nz[j4 * 3 + 4];
  const float4 n2 = *(const float4*)&nz[j4 * 3 + 8];
  float4 o;
  o.x = a0.x * n0.x + a1.x * n0.y + a2.x * n0.z;
  o.y = a0.y * n0.w + a1.y * n1.x + a2.y * n1.y;
  o.z = a0.z * n1.z + a1.z * n1.w + a2.z * n2.x;
  o.w = a0.w * n2.y + a1.w * n2.z + a2.w * n2.w;
  *(float4*)&adj[base] = o;
}

// ---------------------------------------------------------------------------
// k_wsplit: split-bf16 transposed weights (Wq/Wk/Wv + W1).
// ---------------------------------------------------------------------------
__global__ void k_wsplit(const float* __restrict__ Wq, const float* __restrict__ Wk,
                         const float* __restrict__ Wv, const float* __restrict__ W1,
                         u16* __restrict__ WThi, u16* __restrict__ WTlo,
                         u16* __restrict__ W1Thi, u16* __restrict__ W1Tlo) {
  int idx = blockIdx.x * 256 + threadIdx.x;
  if (idx < 49152) {
    int gm = idx >> 14;
    int rem = idx & 16383;
    int col = rem >> 7, k = rem & 127;
    const float* W = (gm == 0) ? Wq : (gm == 1) ? Wk : Wv;
    float v = W[k * NH + col];
    WThi[idx] = hi16(v);
    WTlo[idx] = hi16(v - hif(v));
  } else {
    int rem = idx - 49152;
    int col = rem >> 9, k = rem & 511;
    float v = W1[k * NH + col];
    W1Thi[rem] = hi16(v);
    W1Tlo[rem] = hi16(v - hif(v));
  }
}

// ---------------------------------------------------------------------------
// k_xw1m: xw1 = x @ W1 via split-bf16 MFMA (round-12-verified).
// ---------------------------------------------------------------------------
__global__ __launch_bounds__(256) void k_xw1m(
    const float* __restrict__ x,
    const u16* __restrict__ W1Thi, const u16* __restrict__ W1Tlo,
    u16* __restrict__ xw1Thi, u16* __restrict__ xw1Tlo) {
  __shared__ u16 Ah[64][128];
  __shared__ u16 Al[64][128];
  __shared__ u16 Vst[2][128 * 24];
  int i0 = blockIdx.x * 16;
  int tid = threadIdx.x;
  int w = tid >> 6, l = tid & 63, g = l >> 4, l15 = l & 15;
  {
    int r = tid >> 4, cb = (tid & 15) * 4;
#pragma unroll
    for (int q = 0; q < 4; ++q) {
      int c = cb + q;
      const float4 a0 = *(const float4*)&x[(size_t)(i0 + r) * NF + c * 8];
      const float4 a1 = *(const float4*)&x[(size_t)(i0 + r) * NF + c * 8 + 4];
      bf16x8 hi8, lo8;
      const float* p0 = (const float*)&a0;
      const float* p1 = (const float*)&a1;
#pragma unroll
      for (int e = 0; e < 4; ++e) {
        float v0 = p0[e], v1 = p1[e];
        hi8[e] = (short)hi16(v0); hi8[4 + e] = (short)hi16(v1);
        lo8[e] = (short)hi16(v0 - hif(v0));
        lo8[4 + e] = (short)hi16(v1 - hif(v1));
      }
      *(bf16x8*)&Ah[c][r * 8] = hi8;
      *(bf16x8*)&Al[c][r * 8] = lo8;
    }
  }
  __syncthreads();
  f32x4 acc[2];
  acc[0] = (f32x4){0.f, 0.f, 0.f, 0.f};
  acc[1] = (f32x4){0.f, 0.f, 0.f, 0.f};
#pragma unroll 4
  for (int kb = 0; kb < 16; ++kb) {
    const bf16x8 ah = *(const bf16x8*)&Ah[kb * 4 + g][l15 * 8];
    const bf16x8 al = *(const bf16x8*)&Al[kb * 4 + g][l15 * 8];
#pragma unroll
    for (int cti = 0; cti < 2; ++cti) {
      int col = (2 * w + cti) * 16 + l15;
      const bf16x8 bh = *(const bf16x8*)&W1Thi[col * NF + kb * 32 + 8 * g];
      const bf16x8 bl = *(const bf16x8*)&W1Tlo[col * NF + kb * 32 + 8 * g];
      acc[cti] = __builtin_amdgcn_mfma_f32_16x16x32_bf16(ah, bh, acc[cti], 0, 0, 0);
      acc[cti] = __builtin_amdgcn_mfma_f32_16x16x32_bf16(ah, bl, acc[cti], 0, 0, 0);
      acc[cti] = __builtin_amdgcn_mfma_f32_16x16x32_bf16(al, bh, acc[cti], 0, 0, 0);
    }
  }
#pragma unroll
  for (int cti = 0; cti < 2; ++cti) {
    int col = (2 * w + cti) * 16 + l15;
#pragma unroll
    for (int i = 0; i < 4; ++i) {
      float v = acc[cti][i];
      Vst[0][col * 24 + 4 * g + i] = hi16(v);
      Vst[1][col * 24 + 4 * g + i] = hi16(v - hif(v));
    }
  }
  __syncthreads();
  {
    int d = tid >> 1, half = tid & 1;
    bf16x8 vh = *(const bf16x8*)&Vst[0][d * 24 + half * 8];
    bf16x8 vl = *(const bf16x8*)&Vst[1][d * 24 + half * 8];
    *(bf16x8*)&xw1Thi[(size_t)d * N + i0 + half * 8] = vh;
    *(bf16x8*)&xw1Tlo[(size_t)d * N + i0 + half * 8] = vl;
  }
}

// ---------------------------------------------------------------------------
// glds16: async global -> LDS, 16B per lane.
// ---------------------------------------------------------------------------
__device__ __forceinline__ void glds16(const void* g, void* l) {
  __builtin_amdgcn_global_load_lds(
      (const __attribute__((address_space(1))) void*)g,
      (__attribute__((address_space(3))) void*)l, 16, 0, 0);
}

// ---------------------------------------------------------------------------
// k_h v7: hp_chunk = adj[:, chunk] @ xw1[chunk, :] via split-bf16 MFMA.
// (round-13-verified)
// ---------------------------------------------------------------------------
__global__ __launch_bounds__(512) void k_h(const float* __restrict__ adj,
                                           const u16* __restrict__ xw1Thi,
                                           const u16* __restrict__ xw1Tlo,
                                           float* __restrict__ hp0,
                                           float* __restrict__ hp1,
                                           float* __restrict__ hp2,
                                           float* __restrict__ hp3) {
  __shared__ u16 Ah[8][520];
  __shared__ u16 Al[8][520];
  __shared__ u16 Bh[8][1024];
  __shared__ u16 Bl[8][1024];
  int kbase = blockIdx.x * 1024;
  int i0 = blockIdx.y * 64;
  float* hp = (blockIdx.x == 0) ? hp0 : (blockIdx.x == 1) ? hp1
            : (blockIdx.x == 2) ? hp2 : hp3;
  int tid = threadIdx.x;
  int w = tid >> 6, l = tid & 63, g = l >> 4, l15 = l & 15;
  int rt = w & 3, cg = w >> 2;
  int srow = tid >> 3, sseg = tid & 7;
  int bkk[4], bbuf[4], bcol[4];
#pragma unroll
  for (int q = 0; q < 4; ++q) {
    int idx = w * 4 + q;
    bbuf[q] = idx >> 4; bkk[q] = (idx >> 1) & 7;
    bcol[q] = (idx & 1) * 64 + l;
  }

  float4 av0 = *(const float4*)&adj[(size_t)(i0 + srow) * N + kbase + sseg * 8];
  float4 av1 = *(const float4*)&adj[(size_t)(i0 + srow) * N + kbase + sseg * 8 + 4];
  bf16x8 breg[4];
#pragma unroll
  for (int q = 0; q < 4; ++q) {
    const u16* src = bbuf[q] ? xw1Tlo : xw1Thi;
    breg[q] = *(const bf16x8*)&src[(size_t)bcol[q] * N + kbase + bkk[q] * 8];
  }

  f32x4 acc[4];
#pragma unroll
  for (int nt = 0; nt < 4; ++nt) acc[nt] = (f32x4){0.f, 0.f, 0.f, 0.f};

  for (int t = 0; t < 16; ++t) {
    asm volatile("s_waitcnt lgkmcnt(0)" ::: "memory");
    __builtin_amdgcn_s_barrier();
    {
      bf16x8 hi8, lo8;
      const float* a0p = (const float*)&av0;
      const float* a1p = (const float*)&av1;
#pragma unroll
      for (int e = 0; e < 4; ++e) {
        float v0 = a0p[e], v1 = a1p[e];
        hi8[e] = (short)hi16(v0);     hi8[4 + e] = (short)hi16(v1);
        lo8[e] = (short)hi16(v0 - hif(v0));
        lo8[4 + e] = (short)hi16(v1 - hif(v1));
      }
      *(bf16x8*)&Ah[sseg][srow * 8] = hi8;
      *(bf16x8*)&Al[sseg][srow * 8] = lo8;
    }
#pragma unroll
    for (int q = 0; q < 4; ++q) {
      u16* dst = bbuf[q] ? &Bl[bkk[q]][0] : &Bh[bkk[q]][0];
      *(bf16x8*)&dst[idxB(bcol[q])] = breg[q];
    }
    if (t < 15) {
      int k0n = kbase + (t + 1) * 64;
      av0 = *(const float4*)&adj[(size_t)(i0 + srow) * N + k0n + sseg * 8];
      av1 = *(const float4*)&adj[(size_t)(i0 + srow) * N + k0n + sseg * 8 + 4];
#pragma unroll
      for (int q = 0; q < 4; ++q) {
        const u16* src = bbuf[q] ? xw1Tlo : xw1Thi;
        breg[q] = *(const bf16x8*)&src[(size_t)bcol[q] * N + k0n + bkk[q] * 8];
      }
    }
    asm volatile("s_waitcnt lgkmcnt(0)" ::: "memory");
    __builtin_amdgcn_s_barrier();

#pragma unroll
    for (int kb = 0; kb < 2; ++kb) {
      const bf16x8 ah = *(const bf16x8*)&Ah[kb * 4 + g][(rt * 16 + l15) * 8];
      const bf16x8 al = *(const bf16x8*)&Al[kb * 4 + g][(rt * 16 + l15) * 8];
#pragma unroll
      for (int nt = 0; nt < 4; ++nt) {
        int col = cg * 64 + nt * 16 + l15;
        const bf16x8 bh = *(const bf16x8*)&Bh[kb * 4 + g][idxB(col)];
        const bf16x8 bl = *(const bf16x8*)&Bl[kb * 4 + g][idxB(col)];
        acc[nt] = __builtin_amdgcn_mfma_f32_16x16x32_bf16(ah, bh, acc[nt], 0, 0, 0);
        acc[nt] = __builtin_amdgcn_mfma_f32_16x16x32_bf16(ah, bl, acc[nt], 0, 0, 0);
        acc[nt] = __builtin_amdgcn_mfma_f32_16x16x32_bf16(al, bh, acc[nt], 0, 0, 0);
      }
    }
  }
#pragma unroll
  for (int nt = 0; nt < 4; ++nt)
#pragma unroll
    for (int i = 0; i < 4; ++i)
      hp[(size_t)(i0 + rt * 16 + 4 * g + i) * NH + cg * 64 + nt * 16 + l15] =
          acc[nt][i];
}

// ---------------------------------------------------------------------------
// k_hsum: h = relu(hp0+hp1+hp2+hp3+b1) -> split-bf16 Hhi/Hlo [n][128].
// ---------------------------------------------------------------------------
__global__ void k_hsum(const float* __restrict__ hp0, const float* __restrict__ hp1,
                       const float* __restrict__ hp2, const float* __restrict__ hp3,
                       const float* __restrict__ b1,
                       u16* __restrict__ Hhi, u16* __restrict__ Hlo) {
  int idx = blockIdx.x * 256 + threadIdx.x;
  int gi = idx * 4;
  const float4 v0 = *(const float4*)&hp0[gi];
  const float4 v1 = *(const float4*)&hp1[gi];
  const float4 v2 = *(const float4*)&hp2[gi];
  const float4 v3 = *(const float4*)&hp3[gi];
  const float4 bv = *(const float4*)&b1[gi & (NH - 1)];
  float h[4];
  h[0] = fmaxf(v0.x + v1.x + v2.x + v3.x + bv.x, 0.f);
  h[1] = fmaxf(v0.y + v1.y + v2.y + v3.y + bv.y, 0.f);
  h[2] = fmaxf(v0.z + v1.z + v2.z + v3.z + bv.z, 0.f);
  h[3] = fmaxf(v0.w + v1.w + v2.w + v3.w + bv.w, 0.f);
  u16x4 hi, lo;
#pragma unroll
  for (int e = 0; e < 4; ++e) {
    hi[e] = hi16(h[e]);
    lo[e] = hi16(h[e] - hif(h[e]));
  }
  *(u16x4*)&Hhi[gi] = hi;
  *(u16x4*)&Hlo[gi] = lo;
}

// ---------------------------------------------------------------------------
// k_qkv2: Q/K/V = H @ W{q,k,v} + b via split-bf16 MFMA (round-11-verified).
// ---------------------------------------------------------------------------
__global__ __launch_bounds__(256) void k_qkv2(
    const u16* __restrict__ Hhi, const u16* __restrict__ Hlo,
    const u16* __restrict__ WThi, const u16* __restrict__ WTlo,
    const float* __restrict__ bq, const float* __restrict__ bk,
    const float* __restrict__ bv,
    u16* __restrict__ Qhi, u16* __restrict__ Qlo,
    u16* __restrict__ Khi, u16* __restrict__ Klo,
    u16* __restrict__ VThi, u16* __restrict__ VTlo) {
  __shared__ u16 Vst[2][128 * 24];
  int i0 = blockIdx.x * 16;
  int tid = threadIdx.x;
  int w = tid >> 6, l = tid & 63, g = l >> 4, l15 = l & 15;
  bf16x8 ah[4], al[4];
#pragma unroll
  for (int kb = 0; kb < 4; ++kb) {
    ah[kb] = *(const bf16x8*)&Hhi[(i0 + l15) * NH + kb * 32 + 8 * g];
    al[kb] = *(const bf16x8*)&Hlo[(i0 + l15) * NH + kb * 32 + 8 * g];
  }
#pragma unroll
  for (int gm = 0; gm < 3; ++gm) {
    const u16* wth = WThi + gm * 16384;
    const u16* wtl = WTlo + gm * 16384;
    const float* bb = (gm == 0) ? bq : (gm == 1) ? bk : bv;
#pragma unroll
    for (int cti = 0; cti < 2; ++cti) {
      int ct = 2 * w + cti;
      int col = ct * 16 + l15;
      f32x4 acc = (f32x4){0.f, 0.f, 0.f, 0.f};
#pragma unroll
      for (int kb = 0; kb < 4; ++kb) {
        const bf16x8 bh = *(const bf16x8*)&wth[col * NH + kb * 32 + 8 * g];
        const bf16x8 bl = *(const bf16x8*)&wtl[col * NH + kb * 32 + 8 * g];
        acc = __builtin_amdgcn_mfma_f32_16x16x32_bf16(ah[kb], bh, acc, 0, 0, 0);
        acc = __builtin_amdgcn_mfma_f32_16x16x32_bf16(ah[kb], bl, acc, 0, 0, 0);
        acc = __builtin_amdgcn_mfma_f32_16x16x32_bf16(al[kb], bh, acc, 0, 0, 0);
      }
      float bias = bb[col];
#pragma unroll
      for (int i = 0; i < 4; ++i) {
        float v = acc[i] + bias;
        u16 vh = hi16(v), vl = hi16(v - hif(v));
        int row = i0 + 4 * g + i;
        if (gm == 0) {
          Qhi[row * NH + col] = vh; Qlo[row * NH + col] = vl;
        } else if (gm == 1) {
          Khi[row * NH + col] = vh; Klo[row * NH + col] = vl;
        } else {
          Vst[0][col * 24 + 4 * g + i] = vh;
          Vst[1][col * 24 + 4 * g + i] = vl;
        }
      }
    }
  }
  __syncthreads();
  {
    int d = tid >> 1, half = tid & 1;
    bf16x8 vh = *(const bf16x8*)&Vst[0][d * 24 + half * 8];
    bf16x8 vl = *(const bf16x8*)&Vst[1][d * 24 + half * 8];
    *(bf16x8*)&VThi[(size_t)d * N + i0 + half * 8] = vh;
    *(bf16x8*)&VTlo[(size_t)d * N + i0 + half * 8] = vl;
  }
}

// ---------------------------------------------------------------------------
// k_attn v8: split-bf16 MFMA flash attention, 2 barriers/tile.
// Grid (CSPLIT, 32): BM=128, 512 threads (8 waves), LDS 96 KB.
// P is wave-private (writer rows 16w..16w+15 == reader rows) and DS ops are
// in-order within a wave, so the post-P-write barrier is removed; V staging
// is covered by vmcnt(0) at the pre-QK barrier.  Waves drift across
// QK/softmax/PV (softmax VALU of one wave overlaps PV MFMA of another).
// ---------------------------------------------------------------------------
__global__ __launch_bounds__(512) void k_attn(
    const u16* __restrict__ Qhi, const u16* __restrict__ Qlo,
    const u16* __restrict__ Khi, const u16* __restrict__ Klo,
    const u16* __restrict__ VThi, const u16* __restrict__ VTlo,
    const float* __restrict__ adj,
    float* __restrict__ xp0, float* __restrict__ xp1, float* __restrict__ xp2,
    float* __restrict__ xp3, float* __restrict__ xp4, float* __restrict__ xp5,
    float* __restrict__ xp6, float* __restrict__ xp7,
    float* __restrict__ ml) {
  __shared__ u16 Ks[2][16][512];
  __shared__ u16 Vs[2][8][1024];
  __shared__ u16 Ps[2][8][1024];
  int cid = blockIdx.x;
  int i0 = blockIdx.y * 128;
  int tid = threadIdx.x;
  int w = tid >> 6, l = tid & 63, g = l >> 4, l15 = l & 15;
  int ty = tid >> 4, tx16 = tid & 15;
  float* xp = (cid < 4) ? ((cid < 2) ? (cid == 0 ? xp0 : xp1) : (cid == 2 ? xp2 : xp3))
                        : ((cid < 6) ? (cid == 4 ? xp4 : xp5) : (cid == 6 ? xp6 : xp7));

  bf16x8 qh[4], ql[4];
  {
    const u16* qbh = &Qhi[(i0 + 16 * w + l15) * NH];
    const u16* qbl = &Qlo[(i0 + 16 * w + l15) * NH];
#pragma unroll
    for (int kb = 0; kb < 4; ++kb) {
      qh[kb] = *(const bf16x8*)&qbh[kb * 32 + 8 * g];
      ql[kb] = *(const bf16x8*)&qbl[kb * 32 + 8 * g];
    }
  }

  float m[4], li[4];
  f32x4 Xa[8];
#pragma unroll
  for (int i = 0; i < 4; ++i) { m[i] = -3.0e38f; li[i] = 0.f; }
#pragma unroll
  for (int nt = 0; nt < 8; ++nt) Xa[nt] = (f32x4){0.f, 0.f, 0.f, 0.f};

  for (int jt = 0; jt < 8; ++jt) {
    int j0g = cid * (N / CSPLIT) + jt * 64;
    float adjm[4][4];
#pragma unroll
    for (int i = 0; i < 4; ++i)
#pragma unroll
      for (int ct = 0; ct < 4; ++ct)
        adjm[i][ct] = adj[(size_t)(i0 + 4 * ty + i) * N + j0g + ct * 16 + tx16];
    asm volatile("s_waitcnt lgkmcnt(0)" ::: "memory");  // own prev PV LDS reads done
    __builtin_amdgcn_s_barrier();                       // all waves done w/ Ks,Vs,Ps
#pragma unroll
    for (int q = 0; q < 4; ++q) {
      int idx = w * 4 + q;
      int buf = idx >> 4, c = idx & 15;
      const u16* ks = buf ? Klo : Khi;
      glds16(&ks[(j0g + l) * NH + c * 8], &Ks[buf][c][0]);
    }
#pragma unroll
    for (int q = 0; q < 4; ++q) {
      int idx = w * 4 + q;
      int buf = idx >> 4, cj = (idx >> 1) & 7, h = idx & 1;
      const u16* vsrc = buf ? VTlo : VThi;
      glds16(&vsrc[(h * 64 + l) * N + j0g + cj * 8], &Vs[buf][cj][h * 512]);
    }
    asm volatile("s_waitcnt vmcnt(0)" ::: "memory");    // adj + K + V all landed
    __builtin_amdgcn_s_barrier();                       // full tile staged

    f32x4 acc[4];
#pragma unroll
    for (int ct = 0; ct < 4; ++ct) acc[ct] = (f32x4){0.f, 0.f, 0.f, 0.f};
#pragma unroll
    for (int kb = 0; kb < 4; ++kb) {
#pragma unroll
      for (int ct = 0; ct < 4; ++ct) {
        const bf16x8 kh = *(const bf16x8*)&Ks[0][kb * 4 + g][(ct * 16 + l15) * 8];
        const bf16x8 kl = *(const bf16x8*)&Ks[1][kb * 4 + g][(ct * 16 + l15) * 8];
        acc[ct] = __builtin_amdgcn_mfma_f32_16x16x32_bf16(qh[kb], kh, acc[ct], 0, 0, 0);
        acc[ct] = __builtin_amdgcn_mfma_f32_16x16x32_bf16(qh[kb], kl, acc[ct], 0, 0, 0);
        acc[ct] = __builtin_amdgcn_mfma_f32_16x16x32_bf16(ql[kb], kh, acc[ct], 0, 0, 0);
      }
    }

#pragma unroll
    for (int i = 0; i < 4; ++i) {
      float p[4];
      float s0 = acc[0][i] * adjm[i][0];
      float s1 = acc[1][i] * adjm[i][1];
      float s2 = acc[2][i] * adjm[i][2];
      float s3 = acc[3][i] * adjm[i][3];
      float t = fmaxf(fmaxf(s0, s1), fmaxf(s2, s3));
      t = fmaxf(t, __shfl_xor(t, 1));
      t = fmaxf(t, __shfl_xor(t, 2));
      t = fmaxf(t, __shfl_xor(t, 4));
      t = fmaxf(t, __shfl_xor(t, 8));
      float mn = fmaxf(m[i], t);
      float sc = __expf(m[i] - mn);
      p[0] = __expf(s0 - mn); p[1] = __expf(s1 - mn);
      p[2] = __expf(s2 - mn); p[3] = __expf(s3 - mn);
      float ps = p[0] + p[1] + p[2] + p[3];
      ps += __shfl_xor(ps, 1);
      ps += __shfl_xor(ps, 2);
      ps += __shfl_xor(ps, 4);
      ps += __shfl_xor(ps, 8);
      li[i] = li[i] * sc + ps;
      m[i] = mn;
#pragma unroll
      for (int nt = 0; nt < 8; ++nt) Xa[nt][i] *= sc;
      int row = 4 * ty + i;
#pragma unroll
      for (int ct = 0; ct < 4; ++ct) {
        float pe = p[ct];
        float po = __shfl_xor(pe, 1);
        int cj = ct * 2 + (tx16 >> 3);
        int e = (ct * 16 + tx16) & 7;
        unsigned int hpk = (__float_as_uint(po) & 0xffff0000u)
                         | (__float_as_uint(pe) >> 16);
        float pel = pe - hif(pe), pol = po - hif(po);
        unsigned int lpk = (__float_as_uint(pol) & 0xffff0000u)
                         | (__float_as_uint(pel) >> 16);
        if (!(tx16 & 1)) {
          *(unsigned int*)&Ps[0][cj][row * 8 + e] = hpk;
          *(unsigned int*)&Ps[1][cj][row * 8 + e] = lpk;
        }
      }
    }
    // P is wave-private; DS ops complete in order within a wave -> no barrier.
    asm volatile("s_waitcnt lgkmcnt(0)" ::: "memory");  // own P writes complete

#pragma unroll
    for (int jb = 0; jb < 2; ++jb) {
      const bf16x8 ph = *(const bf16x8*)&Ps[0][jb * 4 + g][(16 * w + l15) * 8];
      const bf16x8 pl = *(const bf16x8*)&Ps[1][jb * 4 + g][(16 * w + l15) * 8];
#pragma unroll
      for (int nt = 0; nt < 8; ++nt) {
        const bf16x8 vh = *(const bf16x8*)&Vs[0][jb * 4 + g][(nt * 16 + l15) * 8];
        const bf16x8 vl = *(const bf16x8*)&Vs[1][jb * 4 + g][(nt * 16 + l15) * 8];
        Xa[nt] = __builtin_amdgcn_mfma_f32_16x16x32_bf16(ph, vh, Xa[nt], 0, 0, 0);
        Xa[nt] = __builtin_amdgcn_mfma_f32_16x16x32_bf16(ph, vl, Xa[nt], 0, 0, 0);
        Xa[nt] = __builtin_amdgcn_mfma_f32_16x16x32_bf16(pl, vh, Xa[nt], 0, 0, 0);
      }
    }
  }

#pragma unroll
  for (int i = 0; i < 4; ++i) {
    int row = i0 + 4 * ty + i;
    float inv = 1.f / li[i];
#pragma unroll
    for (int nt = 0; nt < 8; ++nt)
      xp[row * NH + nt * 16 + tx16] = Xa[nt][i] * inv;
    if (tx16 == 0) {
      ml[(cid * N + row) * 2 + 0] = m[i];
      ml[(cid * N + row) * 2 + 1] = li[i];
    }
  }
}

// ---------------------------------------------------------------------------
// k_comb: merge 8 chunk-partials, normalize, relu -> Xt
// ---------------------------------------------------------------------------
__global__ void k_comb(const float* __restrict__ xp0, const float* __restrict__ xp1,
                       const float* __restrict__ xp2, const float* __restrict__ xp3,
                       const float* __restrict__ xp4, const float* __restrict__ xp5,
                       const float* __restrict__ xp6, const float* __restrict__ xp7,
                       const float* __restrict__ ml, float* __restrict__ Xt) {
  int idx = blockIdx.x * 256 + threadIdx.x;
  int r = idx >> 5, d4 = (idx & 31) << 2;
  float mm[8], ll[8];
#pragma unroll
  for (int c = 0; c < 8; ++c) {
    mm[c] = ml[(c * N + r) * 2 + 0];
    ll[c] = ml[(c * N + r) * 2 + 1];
  }
  float ms = mm[0];
#pragma unroll
  for (int c = 1; c < 8; ++c) ms = fmaxf(ms, mm[c]);
  float e[8], den = 0.f;
#pragma unroll
  for (int c = 0; c < 8; ++c) { e[c] = __expf(mm[c] - ms); den += e[c] * ll[c]; }
  float inv = 1.f / den;
  const float4 a0 = *(const float4*)&xp0[r * NH + d4];
  const float4 a1 = *(const float4*)&xp1[r * NH + d4];
  const float4 a2 = *(const float4*)&xp2[r * NH + d4];
  const float4 a3 = *(const float4*)&xp3[r * NH + d4];
  const float4 a4 = *(const float4*)&xp4[r * NH + d4];
  const float4 a5 = *(const float4*)&xp5[r * NH + d4];
  const float4 a6 = *(const float4*)&xp6[r * NH + d4];
  const float4 a7 = *(const float4*)&xp7[r * NH + d4];
  float4 o;
  o.x = a0.x * e[0] + a1.x * e[1] + a2.x * e[2] + a3.x * e[3]
      + a4.x * e[4] + a5.x * e[5] + a6.x * e[6] + a7.x * e[7];
  o.y = a0.y * e[0] + a1.y * e[1] + a2.y * e[2] + a3.y * e[3]
      + a4.y * e[4] + a5.y * e[5] + a6.y * e[6] + a7.y * e[7];
  o.z = a0.z * e[0] + a1.z * e[1] + a2.z * e[2] + a3.z * e[3]
      + a4.z * e[4] + a5.z * e[5] + a6.z * e[6] + a7.z * e[7];
  o.w = a0.w * e[0] + a1.w * e[1] + a2.w * e[2] + a3.w * e[3]
      + a4.w * e[4] + a5.w * e[5] + a6.w * e[6] + a7.w * e[7];
  o.x = fmaxf(o.x * inv, 0.f); o.y = fmaxf(o.y * inv, 0.f);
  o.z = fmaxf(o.z * inv, 0.f); o.w = fmaxf(o.w * inv, 0.f);
  *(float4*)&Xt[r * NH + d4] = o;
}

// ---------------------------------------------------------------------------
// k_xtw2: xtw2 = Xt @ W2.  16 rows/block, 256 blocks, 256 threads.
// ---------------------------------------------------------------------------
__global__ __launch_bounds__(256) void k_xtw2(const float* __restrict__ Xt,
                                              const float* __restrict__ W2,
                                              float* __restrict__ xtw2) {
  __shared__ float xs[16 * 132];
  __shared__ float w2s[NH * NC];
  int i0 = blockIdx.x * 16;
  int tid = threadIdx.x;
#pragma unroll
  for (int s = 0; s < 2; ++s) {
    int f4 = tid + 256 * s;
    int r = f4 >> 5, k4 = (f4 & 31) << 2;
    const float4 v = *(const float4*)&Xt[(i0 + r) * NH + k4];
    *(float4*)&xs[r * 132 + k4] = v;
    *(float4*)&w2s[f4 * 4] = *(const float4*)&W2[f4 * 4];
  }
  __syncthreads();
  int r = tid >> 4, c = tid & 15;
  float acc = 0.f;
#pragma unroll 8
  for (int k = 0; k < NH; ++k)
    acc += xs[r * 132 + k] * w2s[k * NC + c];
  xtw2[(i0 + r) * NC + c] = acc;
}

// ---------------------------------------------------------------------------
// k_z: z = adj @ xtw2 + b2; out = rowsoftmax(z).  BM=8, 512 blocks.
// ---------------------------------------------------------------------------
__global__ __launch_bounds__(256) void k_z(const float* __restrict__ adj,
                                           const float* __restrict__ xtw2,
                                           const float* __restrict__ b2,
                                           float* __restrict__ out) {
  __shared__ float xwsT[16 * 68];
  int i0 = blockIdx.x * 8;
  int tid = threadIdx.x;
  int ty = tid >> 6, cg = (tid >> 4) & 3, jg = tid & 15;
  int jr = tid >> 2, cq = tid & 3;
  float acc[2][4];
#pragma unroll
  for (int i = 0; i < 2; ++i)
#pragma unroll
    for (int c = 0; c < 4; ++c) acc[i][c] = 0.f;

  for (int j0 = 0; j0 < N; j0 += 64) {
    float4 av[2];
#pragma unroll
    for (int i = 0; i < 2; ++i)
      av[i] = *(const float4*)&adj[(i0 + 2 * ty + i) * N + j0 + 4 * jg];
    const float4 xv = *(const float4*)&xtw2[(j0 + jr) * NC + 4 * cq];
    __syncthreads();
    xwsT[(4 * cq + 0) * 68 + jr] = xv.x;
    xwsT[(4 * cq + 1) * 68 + jr] = xv.y;
    xwsT[(4 * cq + 2) * 68 + jr] = xv.z;
    xwsT[(4 * cq + 3) * 68 + jr] = xv.w;
    __syncthreads();
#pragma unroll
    for (int c = 0; c < 4; ++c) {
      const float4 wv = *(const float4*)&xwsT[(4 * cg + c) * 68 + 4 * jg];
#pragma unroll
      for (int i = 0; i < 2; ++i)
        acc[i][c] += av[i].x * wv.x + av[i].y * wv.y
                   + av[i].z * wv.z + av[i].w * wv.w;
    }
  }
#pragma unroll
  for (int i = 0; i < 2; ++i)
#pragma unroll
    for (int c = 0; c < 4; ++c) {
      float v = acc[i][c];
      v += __shfl_xor(v, 1);
      v += __shfl_xor(v, 2);
      v += __shfl_xor(v, 4);
      v += __shfl_xor(v, 8);
      acc[i][c] = v;
    }
  float bv0 = b2[4 * cg + 0], bv1 = b2[4 * cg + 1];
  float bv2 = b2[4 * cg + 2], bv3 = b2[4 * cg + 3];
#pragma unroll
  for (int i = 0; i < 2; ++i) {
    float z0 = acc[i][0] + bv0, z1 = acc[i][1] + bv1;
    float z2 = acc[i][2] + bv2, z3 = acc[i][3] + bv3;
    float mv = fmaxf(fmaxf(z0, z1), fmaxf(z2, z3));
    mv = fmaxf(mv, __shfl_xor(mv, 16));
    mv = fmaxf(mv, __shfl_xor(mv, 32));
    float e0 = __expf(z0 - mv), e1 = __expf(z1 - mv);
    float e2 = __expf(z2 - mv), e3 = __expf(z3 - mv);
    float s = e0 + e1 + e2 + e3;
    s += __shfl_xor(s, 16);
    s += __shfl_xor(s, 32);
    if (jg == 0) {
      float4 o = {e0 / s, e1 / s, e2 / s, e3 / s};
      *(float4*)&out[(i0 + 2 * ty + i) * NC + 4 * cg] = o;
    }
  }
}

// ---------------------------------------------------------------------------
extern "C" void kernel_launch(void* const* d_in, const int* in_sizes, int n_in,
                              void* d_out, int out_size, void* d_ws, size_t ws_size,
                              hipStream_t stream) {
  const float* A0  = (const float*)d_in[0];
  const float* A1  = (const float*)d_in[1];
  const float* A2  = (const float*)d_in[2];
  const float* x   = (const float*)d_in[3];
  const float* Wa1 = (const float*)d_in[4];  const float* ba1 = (const float*)d_in[5];
  const float* Wa2 = (const float*)d_in[6];  const float* ba2 = (const float*)d_in[7];
  const float* Wa3 = (const float*)d_in[8];  const float* ba3 = (const float*)d_in[9];
  const float* Wagg = (const float*)d_in[10]; const float* bagg = (const float*)d_in[11];
  const float* W1  = (const float*)d_in[12]; const float* b1  = (const float*)d_in[13];
  const float* Wq  = (const float*)d_in[14]; const float* bq  = (const float*)d_in[15];
  const float* Wk  = (const float*)d_in[16]; const float* bk  = (const float*)d_in[17];
  const float* Wv  = (const float*)d_in[18]; const float* bv  = (const float*)d_in[19];
  const float* W2  = (const float*)d_in[20]; const float* b2  = (const float*)d_in[21];

  float* out0 = (float*)d_out;            // [N,16] class softmax
  float* nz   = out0 + N * NC;            // [N,3] mixing weights (output 1)

  float* ws   = (float*)d_ws;
  float* adj  = ws;                       // N*N
  float* Wc2  = adj + (size_t)N * N;      // 3*N*4
  float* bz   = Wc2 + 3 * N * 4;          // 16
  float* xw1  = bz + 16;                  // N*NH region -> xw1T bf16 / attn xp0
  float* hpre = xw1 + N * NH;             // N*NH  (h partial 0 / attn xp1)
  float* QhT  = hpre + N * NH;            // N*NH region: zp | W1T planes | Qhi/Qlo
  float* KhT  = QhT + N * NH;             // N*NH region -> Khi/Klo bf16
  float* Vh   = KhT + N * NH;             // N*NH region -> VThi/VTlo bf16
  float* Xt   = Vh + N * NH;              // N*NH  (H planes, then attn xp7/Xt)
  float* xtw2 = Xt + N * NH;              // N*NC  (WT planes, then xtw2)
  float* P2   = xtw2 + N * NC;            // h partial 1 / attn xp2
  float* P3   = P2 + N * NH;              // h partial 2 / attn xp3
  float* P4   = P3 + N * NH;              // h partial 3 / attn xp4
  float* P5   = P4 + N * NH;
  float* P6   = P5 + N * NH;
  float* ml   = P6 + N * NH;              // 8*N*2
  float* zp   = QhT;                      // [N][12] f32 = 192 KB (head of QhT)

  u16* xw1Thi = (u16*)xw1; u16* xw1Tlo = xw1Thi + (size_t)N * NH;
  u16* Qhi  = (u16*)QhT; u16* Qlo = Qhi + (size_t)N * NH;
  u16* Khi  = (u16*)KhT; u16* Klo = Khi + (size_t)N * NH;
  u16* VThi = (u16*)Vh;  u16* VTlo = VThi + (size_t)N * NH;
  u16* Hhi  = (u16*)Xt;  u16* Hlo = Hhi + (size_t)N * NH;
  u16* WThi = (u16*)xtw2; u16* WTlo = WThi + (size_t)3 * NH * NH;
  u16* W1Thi = (u16*)(QhT + 65536); u16* W1Tlo = W1Thi + (size_t)NF * NH;

  hipLaunchKernelGGL(k_wc, dim3(48), dim3(256), 0, stream,
                     Wa1, Wa2, Wa3, Wagg, ba1, ba2, ba3, bagg, Wc2, bz);
  hipLaunchKernelGGL(k_wsplit, dim3(448), dim3(256), 0, stream,
                     Wq, Wk, Wv, W1, WThi, WTlo, W1Thi, W1Tlo);
  hipLaunchKernelGGL(k_z4p, dim3(N / 4, 3), dim3(256), 0, stream,
                     A0, A1, A2, Wc2, zp);
  hipLaunchKernelGGL(k_nz, dim3(N / 256), dim3(256), 0, stream, zp, bz, nz);
  hipLaunchKernelGGL(k_adj, dim3(N * N / 4 / 256), dim3(256), 0, stream,
                     A0, A1, A2, nz, adj);
  hipLaunchKernelGGL(k_xw1m, dim3(N / 16), dim3(256), 0, stream,
                     x, W1Thi, W1Tlo, xw1Thi, xw1Tlo);
  hipLaunchKernelGGL(k_h, dim3(4, N / 64), dim3(512), 0, stream,
                     adj, xw1Thi, xw1Tlo, hpre, P2, P3, P4);
  hipLaunchKernelGGL(k_hsum, dim3(N * NH / 4 / 256), dim3(256), 0, stream,
                     hpre, P2, P3, P4, b1, Hhi, Hlo);
  hipLaunchKernelGGL(k_qkv2, dim3(N / 16), dim3(256), 0, stream,
                     Hhi, Hlo, WThi, WTlo, bq, bk, bv,
                     Qhi, Qlo, Khi, Klo, VThi, VTlo);
  hipLaunchKernelGGL(k_attn, dim3(CSPLIT, N / 128), dim3(512), 0, stream,
                     Qhi, Qlo, Khi, Klo, VThi, VTlo, adj,
                     xw1, hpre, P2, P3, P4, P5, P6, Xt, ml);
  hipLaunchKernelGGL(k_comb, dim3(N * NH / 4 / 256), dim3(256), 0, stream,
                     xw1, hpre, P2, P3, P4, P5, P6, Xt, ml, Xt);
  hipLaunchKernelGGL(k_xtw2, dim3(N / 16), dim3(256), 0, stream, Xt, W2, xtw2);
  hipLaunchKernelGGL(k_z, dim3(N / 8), dim3(256), 0, stream, adj, xtw2, b2, out0);
}

// Round 17
// 257.860 us; speedup vs baseline: 1.0883x; 1.0097x over previous
//
#include <hip/hip_runtime.h>
#include <math.h>

#define N 4096
#define NF 512
#define NH 128
#define NC 16
#define CSPLIT 8

typedef unsigned short u16;
typedef __attribute__((ext_vector_type(4))) unsigned short u16x4;
typedef __attribute__((ext_vector_type(8))) short bf16x8;
typedef __attribute__((ext_vector_type(4))) float f32x4;

__device__ __forceinline__ u16 hi16(float v) {
  return (u16)(__float_as_uint(v) >> 16);
}
__device__ __forceinline__ float hif(float v) {
  return __uint_as_float(__float_as_uint(v) & 0xffff0000u);
}
// B-plane swizzled u16 index: byte = col*16 ^ ((col&0x38)<<1)
__device__ __forceinline__ int idxB(int col) {
  return (col * 8) ^ (col & 0x38);
}

// ---------------------------------------------------------------------------
// k_wc: Wc2[k][j][4] = {sum_t Wa_k[j,t]*Wagg[k*64+t, c]}  (float4-aligned)
// ---------------------------------------------------------------------------
__global__ void k_wc(const float* __restrict__ Wa1, const float* __restrict__ Wa2,
                     const float* __restrict__ Wa3, const float* __restrict__ Wagg,
                     const float* __restrict__ ba1, const float* __restrict__ ba2,
                     const float* __restrict__ ba3, const float* __restrict__ bagg,
                     float* __restrict__ Wc2, float* __restrict__ bz) {
  int idx = blockIdx.x * 256 + threadIdx.x;
  if (idx < 3 * N) {
    int k = idx >> 12;
    int j = idx & (N - 1);
    const float* Wa = (k == 0) ? Wa1 : (k == 1) ? Wa2 : Wa3;
    float a0 = 0.f, a1 = 0.f, a2 = 0.f;
    for (int t = 0; t < 64; ++t) {
      float w = Wa[j * 64 + t];
      const float* wg = Wagg + (k * 64 + t) * 3;
      a0 += w * wg[0]; a1 += w * wg[1]; a2 += w * wg[2];
    }
    float4 o = {a0, a1, a2, 0.f};
    *(float4*)&Wc2[(k * N + j) * 4] = o;
  }
  if (blockIdx.x == 0 && threadIdx.x < 3) {
    int c = threadIdx.x;
    float acc = bagg[c];
    for (int t = 0; t < 64; ++t) {
      acc += ba1[t] * Wagg[t * 3 + c]
           + ba2[t] * Wagg[(64 + t) * 3 + c]
           + ba3[t] * Wagg[(128 + t) * 3 + c];
    }
    bz[c] = acc;
  }
}

// ---------------------------------------------------------------------------
// k_z4p v3: z4 partials, all 3 matrices.  Grid (1024, 3), 256 threads.
// All 16 A float4 loads hoisted & issued first (16 outstanding HBM loads per
// thread); Wck loads (L2-resident) after; accumulation last.
// ---------------------------------------------------------------------------
__global__ __launch_bounds__(256) void k_z4p(const float* __restrict__ A0,
                                             const float* __restrict__ A1,
                                             const float* __restrict__ A2,
                                             const float* __restrict__ Wc2,
                                             float* __restrict__ zp) {
  __shared__ float red[4][3][4];
  const float* A = (blockIdx.y == 0) ? A0 : (blockIdx.y == 1) ? A1 : A2;
  const float* Wck = Wc2 + (size_t)blockIdx.y * N * 4;
  float* zpk = zp + blockIdx.y * 3;
  int r0 = blockIdx.x * 4;
  int tid = threadIdx.x;
  int lane = tid & 63, wv = tid >> 6;

  // issue ALL A loads first (independent; HBM latency fully overlapped)
  float4 av[16];
#pragma unroll
  for (int s = 0; s < 4; ++s) {
    int j4 = s * 1024 + tid * 4;
#pragma unroll
    for (int r = 0; r < 4; ++r)
      av[s * 4 + r] = *(const float4*)&A[(size_t)(r0 + r) * N + j4];
  }
  // Wck loads (L2-resident)
  float4 wv4[16];
#pragma unroll
  for (int s = 0; s < 4; ++s) {
    int j4 = s * 1024 + tid * 4;
#pragma unroll
    for (int q = 0; q < 4; ++q)
      wv4[s * 4 + q] = *(const float4*)&Wck[(j4 + q) * 4];
  }

  float acc[4][3];
#pragma unroll
  for (int r = 0; r < 4; ++r) { acc[r][0] = 0.f; acc[r][1] = 0.f; acc[r][2] = 0.f; }
#pragma unroll
  for (int s = 0; s < 4; ++s) {
    const float4 w0 = wv4[s * 4 + 0];
    const float4 w1 = wv4[s * 4 + 1];
    const float4 w2 = wv4[s * 4 + 2];
    const float4 w3 = wv4[s * 4 + 3];
#pragma unroll
    for (int r = 0; r < 4; ++r) {
      const float4 a = av[s * 4 + r];
      acc[r][0] += a.x * w0.x + a.y * w1.x + a.z * w2.x + a.w * w3.x;
      acc[r][1] += a.x * w0.y + a.y * w1.y + a.z * w2.y + a.w * w3.y;
      acc[r][2] += a.x * w0.z + a.y * w1.z + a.z * w2.z + a.w * w3.z;
    }
  }
#pragma unroll
  for (int r = 0; r < 4; ++r) {
#pragma unroll
    for (int c = 0; c < 3; ++c) {
      float v = acc[r][c];
      v += __shfl_xor(v, 1);
      v += __shfl_xor(v, 2);
      v += __shfl_xor(v, 4);
      v += __shfl_xor(v, 8);
      v += __shfl_xor(v, 16);
      v += __shfl_xor(v, 32);
      if (lane == 0) red[r][c][wv] = v;
    }
  }
  __syncthreads();
  if (tid < 12) {
    int r = tid / 3; int c = tid - 3 * r;
    zpk[(r0 + r) * 12 + c] =
        red[r][c][0] + red[r][c][1] + red[r][c][2] + red[r][c][3];
  }
}

// ---------------------------------------------------------------------------
// k_nz: z4 = sum of 3 matrix partials + bz; 3-way softmax -> nz
// ---------------------------------------------------------------------------
__global__ void k_nz(const float* __restrict__ zp, const float* __restrict__ bz,
                     float* __restrict__ nz) {
  int row = blockIdx.x * 256 + threadIdx.x;
  const float* p = zp + row * 12;
  float z0 = p[0] + p[3] + p[6] + bz[0];
  float z1 = p[1] + p[4] + p[7] + bz[1];
  float z2 = p[2] + p[5] + p[8] + bz[2];
  float m = fmaxf(z0, fmaxf(z1, z2));
  float e0 = __expf(z0 - m), e1 = __expf(z1 - m), e2 = __expf(z2 - m);
  float s = e0 + e1 + e2;
  float* o = nz + row * 3;
  o[0] = e0 / s; o[1] = e1 / s; o[2] = e2 / s;
}

// ---------------------------------------------------------------------------
// k_adj: adj[i,j] = A0*nz[j,0] + A1*nz[j,1] + A2*nz[j,2]  (column-broadcast)
// ---------------------------------------------------------------------------
__global__ void k_adj(const float* __restrict__ A0, const float* __restrict__ A1,
                      const float* __restrict__ A2, const float* __restrict__ nz,
                      float* __restrict__ adj) {
  int idx = blockIdx.x * 256 + threadIdx.x;
  int i = idx >> 10;
  int j4 = (idx & 1023) << 2;
  int base = i * N + j4;
  const float4 a0 = *(const float4*)&A0[base];
  const float4 a1 = *(const float4*)&A1[base];
  const float4 a2 = *(const float4*)&A2[base];
  const float4 n0 = *(const float4*)&nz[j4 * 3];
  const float4 n1 = *(const float4*)&nz[j4 * 3 + 4];
  const float4 n2 = *(const float4*)&nz[j4 * 3 + 8];
  float4 o;
  o.x = a0.x * n0.x + a1.x * n0.y + a2.x * n0.z;
  o.y = a0.y * n0.w + a1.y * n1.x + a2.y * n1.y;
  o.z = a0.z * n1.z + a1.z * n1.w + a2.z * n2.x;
  o.w = a0.w * n2.y + a1.w * n2.z + a2.w * n2.w;
  *(float4*)&adj[base] = o;
}

// ---------------------------------------------------------------------------
// k_wsplit: split-bf16 transposed weights (Wq/Wk/Wv + W1).
// ---------------------------------------------------------------------------
__global__ void k_wsplit(const float* __restrict__ Wq, const float* __restrict__ Wk,
                         const float* __restrict__ Wv, const float* __restrict__ W1,
                         u16* __restrict__ WThi, u16* __restrict__ WTlo,
                         u16* __restrict__ W1Thi, u16* __restrict__ W1Tlo) {
  int idx = blockIdx.x * 256 + threadIdx.x;
  if (idx < 49152) {
    int gm = idx >> 14;
    int rem = idx & 16383;
    int col = rem >> 7, k = rem & 127;
    const float* W = (gm == 0) ? Wq : (gm == 1) ? Wk : Wv;
    float v = W[k * NH + col];
    WThi[idx] = hi16(v);
    WTlo[idx] = hi16(v - hif(v));
  } else {
    int rem = idx - 49152;
    int col = rem >> 9, k = rem & 511;
    float v = W1[k * NH + col];
    W1Thi[rem] = hi16(v);
    W1Tlo[rem] = hi16(v - hif(v));
  }
}

// ---------------------------------------------------------------------------
// k_xw1m: xw1 = x @ W1 via split-bf16 MFMA (round-12-verified).
// ---------------------------------------------------------------------------
__global__ __launch_bounds__(256) void k_xw1m(
    const float* __restrict__ x,
    const u16* __restrict__ W1Thi, const u16* __restrict__ W1Tlo,
    u16* __restrict__ xw1Thi, u16* __restrict__ xw1Tlo) {
  __shared__ u16 Ah[64][128];
  __shared__ u16 Al[64][128];
  __shared__ u16 Vst[2][128 * 24];
  int i0 = blockIdx.x * 16;
  int tid = threadIdx.x;
  int w = tid >> 6, l = tid & 63, g = l >> 4, l15 = l & 15;
  {
    int r = tid >> 4, cb = (tid & 15) * 4;
#pragma unroll
    for (int q = 0; q < 4; ++q) {
      int c = cb + q;
      const float4 a0 = *(const float4*)&x[(size_t)(i0 + r) * NF + c * 8];
      const float4 a1 = *(const float4*)&x[(size_t)(i0 + r) * NF + c * 8 + 4];
      bf16x8 hi8, lo8;
      const float* p0 = (const float*)&a0;
      const float* p1 = (const float*)&a1;
#pragma unroll
      for (int e = 0; e < 4; ++e) {
        float v0 = p0[e], v1 = p1[e];
        hi8[e] = (short)hi16(v0); hi8[4 + e] = (short)hi16(v1);
        lo8[e] = (short)hi16(v0 - hif(v0));
        lo8[4 + e] = (short)hi16(v1 - hif(v1));
      }
      *(bf16x8*)&Ah[c][r * 8] = hi8;
      *(bf16x8*)&Al[c][r * 8] = lo8;
    }
  }
  __syncthreads();
  f32x4 acc[2];
  acc[0] = (f32x4){0.f, 0.f, 0.f, 0.f};
  acc[1] = (f32x4){0.f, 0.f, 0.f, 0.f};
#pragma unroll 4
  for (int kb = 0; kb < 16; ++kb) {
    const bf16x8 ah = *(const bf16x8*)&Ah[kb * 4 + g][l15 * 8];
    const bf16x8 al = *(const bf16x8*)&Al[kb * 4 + g][l15 * 8];
#pragma unroll
    for (int cti = 0; cti < 2; ++cti) {
      int col = (2 * w + cti) * 16 + l15;
      const bf16x8 bh = *(const bf16x8*)&W1Thi[col * NF + kb * 32 + 8 * g];
      const bf16x8 bl = *(const bf16x8*)&W1Tlo[col * NF + kb * 32 + 8 * g];
      acc[cti] = __builtin_amdgcn_mfma_f32_16x16x32_bf16(ah, bh, acc[cti], 0, 0, 0);
      acc[cti] = __builtin_amdgcn_mfma_f32_16x16x32_bf16(ah, bl, acc[cti], 0, 0, 0);
      acc[cti] = __builtin_amdgcn_mfma_f32_16x16x32_bf16(al, bh, acc[cti], 0, 0, 0);
    }
  }
#pragma unroll
  for (int cti = 0; cti < 2; ++cti) {
    int col = (2 * w + cti) * 16 + l15;
#pragma unroll
    for (int i = 0; i < 4; ++i) {
      float v = acc[cti][i];
      Vst[0][col * 24 + 4 * g + i] = hi16(v);
      Vst[1][col * 24 + 4 * g + i] = hi16(v - hif(v));
    }
  }
  __syncthreads();
  {
    int d = tid >> 1, half = tid & 1;
    bf16x8 vh = *(const bf16x8*)&Vst[0][d * 24 + half * 8];
    bf16x8 vl = *(const bf16x8*)&Vst[1][d * 24 + half * 8];
    *(bf16x8*)&xw1Thi[(size_t)d * N + i0 + half * 8] = vh;
    *(bf16x8*)&xw1Tlo[(size_t)d * N + i0 + half * 8] = vl;
  }
}

// ---------------------------------------------------------------------------
// glds16: async global -> LDS, 16B per lane.
// ---------------------------------------------------------------------------
__device__ __forceinline__ void glds16(const void* g, void* l) {
  __builtin_amdgcn_global_load_lds(
      (const __attribute__((address_space(1))) void*)g,
      (__attribute__((address_space(3))) void*)l, 16, 0, 0);
}

// ---------------------------------------------------------------------------
// k_h v7: hp_chunk = adj[:, chunk] @ xw1[chunk, :] via split-bf16 MFMA.
// (round-13-verified)
// ---------------------------------------------------------------------------
__global__ __launch_bounds__(512) void k_h(const float* __restrict__ adj,
                                           const u16* __restrict__ xw1Thi,
                                           const u16* __restrict__ xw1Tlo,
                                           float* __restrict__ hp0,
                                           float* __restrict__ hp1,
                                           float* __restrict__ hp2,
                                           float* __restrict__ hp3) {
  __shared__ u16 Ah[8][520];
  __shared__ u16 Al[8][520];
  __shared__ u16 Bh[8][1024];
  __shared__ u16 Bl[8][1024];
  int kbase = blockIdx.x * 1024;
  int i0 = blockIdx.y * 64;
  float* hp = (blockIdx.x == 0) ? hp0 : (blockIdx.x == 1) ? hp1
            : (blockIdx.x == 2) ? hp2 : hp3;
  int tid = threadIdx.x;
  int w = tid >> 6, l = tid & 63, g = l >> 4, l15 = l & 15;
  int rt = w & 3, cg = w >> 2;
  int srow = tid >> 3, sseg = tid & 7;
  int bkk[4], bbuf[4], bcol[4];
#pragma unroll
  for (int q = 0; q < 4; ++q) {
    int idx = w * 4 + q;
    bbuf[q] = idx >> 4; bkk[q] = (idx >> 1) & 7;
    bcol[q] = (idx & 1) * 64 + l;
  }

  float4 av0 = *(const float4*)&adj[(size_t)(i0 + srow) * N + kbase + sseg * 8];
  float4 av1 = *(const float4*)&adj[(size_t)(i0 + srow) * N + kbase + sseg * 8 + 4];
  bf16x8 breg[4];
#pragma unroll
  for (int q = 0; q < 4; ++q) {
    const u16* src = bbuf[q] ? xw1Tlo : xw1Thi;
    breg[q] = *(const bf16x8*)&src[(size_t)bcol[q] * N + kbase + bkk[q] * 8];
  }

  f32x4 acc[4];
#pragma unroll
  for (int nt = 0; nt < 4; ++nt) acc[nt] = (f32x4){0.f, 0.f, 0.f, 0.f};

  for (int t = 0; t < 16; ++t) {
    asm volatile("s_waitcnt lgkmcnt(0)" ::: "memory");
    __builtin_amdgcn_s_barrier();
    {
      bf16x8 hi8, lo8;
      const float* a0p = (const float*)&av0;
      const float* a1p = (const float*)&av1;
#pragma unroll
      for (int e = 0; e < 4; ++e) {
        float v0 = a0p[e], v1 = a1p[e];
        hi8[e] = (short)hi16(v0);     hi8[4 + e] = (short)hi16(v1);
        lo8[e] = (short)hi16(v0 - hif(v0));
        lo8[4 + e] = (short)hi16(v1 - hif(v1));
      }
      *(bf16x8*)&Ah[sseg][srow * 8] = hi8;
      *(bf16x8*)&Al[sseg][srow * 8] = lo8;
    }
#pragma unroll
    for (int q = 0; q < 4; ++q) {
      u16* dst = bbuf[q] ? &Bl[bkk[q]][0] : &Bh[bkk[q]][0];
      *(bf16x8*)&dst[idxB(bcol[q])] = breg[q];
    }
    if (t < 15) {
      int k0n = kbase + (t + 1) * 64;
      av0 = *(const float4*)&adj[(size_t)(i0 + srow) * N + k0n + sseg * 8];
      av1 = *(const float4*)&adj[(size_t)(i0 + srow) * N + k0n + sseg * 8 + 4];
#pragma unroll
      for (int q = 0; q < 4; ++q) {
        const u16* src = bbuf[q] ? xw1Tlo : xw1Thi;
        breg[q] = *(const bf16x8*)&src[(size_t)bcol[q] * N + k0n + bkk[q] * 8];
      }
    }
    asm volatile("s_waitcnt lgkmcnt(0)" ::: "memory");
    __builtin_amdgcn_s_barrier();

#pragma unroll
    for (int kb = 0; kb < 2; ++kb) {
      const bf16x8 ah = *(const bf16x8*)&Ah[kb * 4 + g][(rt * 16 + l15) * 8];
      const bf16x8 al = *(const bf16x8*)&Al[kb * 4 + g][(rt * 16 + l15) * 8];
#pragma unroll
      for (int nt = 0; nt < 4; ++nt) {
        int col = cg * 64 + nt * 16 + l15;
        const bf16x8 bh = *(const bf16x8*)&Bh[kb * 4 + g][idxB(col)];
        const bf16x8 bl = *(const bf16x8*)&Bl[kb * 4 + g][idxB(col)];
        acc[nt] = __builtin_amdgcn_mfma_f32_16x16x32_bf16(ah, bh, acc[nt], 0, 0, 0);
        acc[nt] = __builtin_amdgcn_mfma_f32_16x16x32_bf16(ah, bl, acc[nt], 0, 0, 0);
        acc[nt] = __builtin_amdgcn_mfma_f32_16x16x32_bf16(al, bh, acc[nt], 0, 0, 0);
      }
    }
  }
#pragma unroll
  for (int nt = 0; nt < 4; ++nt)
#pragma unroll
    for (int i = 0; i < 4; ++i)
      hp[(size_t)(i0 + rt * 16 + 4 * g + i) * NH + cg * 64 + nt * 16 + l15] =
          acc[nt][i];
}

// ---------------------------------------------------------------------------
// k_hsum: h = relu(hp0+hp1+hp2+hp3+b1) -> split-bf16 Hhi/Hlo [n][128].
// ---------------------------------------------------------------------------
__global__ void k_hsum(const float* __restrict__ hp0, const float* __restrict__ hp1,
                       const float* __restrict__ hp2, const float* __restrict__ hp3,
                       const float* __restrict__ b1,
                       u16* __restrict__ Hhi, u16* __restrict__ Hlo) {
  int idx = blockIdx.x * 256 + threadIdx.x;
  int gi = idx * 4;
  const float4 v0 = *(const float4*)&hp0[gi];
  const float4 v1 = *(const float4*)&hp1[gi];
  const float4 v2 = *(const float4*)&hp2[gi];
  const float4 v3 = *(const float4*)&hp3[gi];
  const float4 bv = *(const float4*)&b1[gi & (NH - 1)];
  float h[4];
  h[0] = fmaxf(v0.x + v1.x + v2.x + v3.x + bv.x, 0.f);
  h[1] = fmaxf(v0.y + v1.y + v2.y + v3.y + bv.y, 0.f);
  h[2] = fmaxf(v0.z + v1.z + v2.z + v3.z + bv.z, 0.f);
  h[3] = fmaxf(v0.w + v1.w + v2.w + v3.w + bv.w, 0.f);
  u16x4 hi, lo;
#pragma unroll
  for (int e = 0; e < 4; ++e) {
    hi[e] = hi16(h[e]);
    lo[e] = hi16(h[e] - hif(h[e]));
  }
  *(u16x4*)&Hhi[gi] = hi;
  *(u16x4*)&Hlo[gi] = lo;
}

// ---------------------------------------------------------------------------
// k_qkv2: Q/K/V = H @ W{q,k,v} + b via split-bf16 MFMA (round-11-verified).
// ---------------------------------------------------------------------------
__global__ __launch_bounds__(256) void k_qkv2(
    const u16* __restrict__ Hhi, const u16* __restrict__ Hlo,
    const u16* __restrict__ WThi, const u16* __restrict__ WTlo,
    const float* __restrict__ bq, const float* __restrict__ bk,
    const float* __restrict__ bv,
    u16* __restrict__ Qhi, u16* __restrict__ Qlo,
    u16* __restrict__ Khi, u16* __restrict__ Klo,
    u16* __restrict__ VThi, u16* __restrict__ VTlo) {
  __shared__ u16 Vst[2][128 * 24];
  int i0 = blockIdx.x * 16;
  int tid = threadIdx.x;
  int w = tid >> 6, l = tid & 63, g = l >> 4, l15 = l & 15;
  bf16x8 ah[4], al[4];
#pragma unroll
  for (int kb = 0; kb < 4; ++kb) {
    ah[kb] = *(const bf16x8*)&Hhi[(i0 + l15) * NH + kb * 32 + 8 * g];
    al[kb] = *(const bf16x8*)&Hlo[(i0 + l15) * NH + kb * 32 + 8 * g];
  }
#pragma unroll
  for (int gm = 0; gm < 3; ++gm) {
    const u16* wth = WThi + gm * 16384;
    const u16* wtl = WTlo + gm * 16384;
    const float* bb = (gm == 0) ? bq : (gm == 1) ? bk : bv;
#pragma unroll
    for (int cti = 0; cti < 2; ++cti) {
      int ct = 2 * w + cti;
      int col = ct * 16 + l15;
      f32x4 acc = (f32x4){0.f, 0.f, 0.f, 0.f};
#pragma unroll
      for (int kb = 0; kb < 4; ++kb) {
        const bf16x8 bh = *(const bf16x8*)&wth[col * NH + kb * 32 + 8 * g];
        const bf16x8 bl = *(const bf16x8*)&wtl[col * NH + kb * 32 + 8 * g];
        acc = __builtin_amdgcn_mfma_f32_16x16x32_bf16(ah[kb], bh, acc, 0, 0, 0);
        acc = __builtin_amdgcn_mfma_f32_16x16x32_bf16(ah[kb], bl, acc, 0, 0, 0);
        acc = __builtin_amdgcn_mfma_f32_16x16x32_bf16(al[kb], bh, acc, 0, 0, 0);
      }
      float bias = bb[col];
#pragma unroll
      for (int i = 0; i < 4; ++i) {
        float v = acc[i] + bias;
        u16 vh = hi16(v), vl = hi16(v - hif(v));
        int row = i0 + 4 * g + i;
        if (gm == 0) {
          Qhi[row * NH + col] = vh; Qlo[row * NH + col] = vl;
        } else if (gm == 1) {
          Khi[row * NH + col] = vh; Klo[row * NH + col] = vl;
        } else {
          Vst[0][col * 24 + 4 * g + i] = vh;
          Vst[1][col * 24 + 4 * g + i] = vl;
        }
      }
    }
  }
  __syncthreads();
  {
    int d = tid >> 1, half = tid & 1;
    bf16x8 vh = *(const bf16x8*)&Vst[0][d * 24 + half * 8];
    bf16x8 vl = *(const bf16x8*)&Vst[1][d * 24 + half * 8];
    *(bf16x8*)&VThi[(size_t)d * N + i0 + half * 8] = vh;
    *(bf16x8*)&VTlo[(size_t)d * N + i0 + half * 8] = vl;
  }
}

// ---------------------------------------------------------------------------
// k_attn v8: split-bf16 MFMA flash attention, 2 barriers/tile
// (round-16-verified).
// ---------------------------------------------------------------------------
__global__ __launch_bounds__(512) void k_attn(
    const u16* __restrict__ Qhi, const u16* __restrict__ Qlo,
    const u16* __restrict__ Khi, const u16* __restrict__ Klo,
    const u16* __restrict__ VThi, const u16* __restrict__ VTlo,
    const float* __restrict__ adj,
    float* __restrict__ xp0, float* __restrict__ xp1, float* __restrict__ xp2,
    float* __restrict__ xp3, float* __restrict__ xp4, float* __restrict__ xp5,
    float* __restrict__ xp6, float* __restrict__ xp7,
    float* __restrict__ ml) {
  __shared__ u16 Ks[2][16][512];
  __shared__ u16 Vs[2][8][1024];
  __shared__ u16 Ps[2][8][1024];
  int cid = blockIdx.x;
  int i0 = blockIdx.y * 128;
  int tid = threadIdx.x;
  int w = tid >> 6, l = tid & 63, g = l >> 4, l15 = l & 15;
  int ty = tid >> 4, tx16 = tid & 15;
  float* xp = (cid < 4) ? ((cid < 2) ? (cid == 0 ? xp0 : xp1) : (cid == 2 ? xp2 : xp3))
                        : ((cid < 6) ? (cid == 4 ? xp4 : xp5) : (cid == 6 ? xp6 : xp7));

  bf16x8 qh[4], ql[4];
  {
    const u16* qbh = &Qhi[(i0 + 16 * w + l15) * NH];
    const u16* qbl = &Qlo[(i0 + 16 * w + l15) * NH];
#pragma unroll
    for (int kb = 0; kb < 4; ++kb) {
      qh[kb] = *(const bf16x8*)&qbh[kb * 32 + 8 * g];
      ql[kb] = *(const bf16x8*)&qbl[kb * 32 + 8 * g];
    }
  }

  float m[4], li[4];
  f32x4 Xa[8];
#pragma unroll
  for (int i = 0; i < 4; ++i) { m[i] = -3.0e38f; li[i] = 0.f; }
#pragma unroll
  for (int nt = 0; nt < 8; ++nt) Xa[nt] = (f32x4){0.f, 0.f, 0.f, 0.f};

  for (int jt = 0; jt < 8; ++jt) {
    int j0g = cid * (N / CSPLIT) + jt * 64;
    float adjm[4][4];
#pragma unroll
    for (int i = 0; i < 4; ++i)
#pragma unroll
      for (int ct = 0; ct < 4; ++ct)
        adjm[i][ct] = adj[(size_t)(i0 + 4 * ty + i) * N + j0g + ct * 16 + tx16];
    asm volatile("s_waitcnt lgkmcnt(0)" ::: "memory");
    __builtin_amdgcn_s_barrier();
#pragma unroll
    for (int q = 0; q < 4; ++q) {
      int idx = w * 4 + q;
      int buf = idx >> 4, c = idx & 15;
      const u16* ks = buf ? Klo : Khi;
      glds16(&ks[(j0g + l) * NH + c * 8], &Ks[buf][c][0]);
    }
#pragma unroll
    for (int q = 0; q < 4; ++q) {
      int idx = w * 4 + q;
      int buf = idx >> 4, cj = (idx >> 1) & 7, h = idx & 1;
      const u16* vsrc = buf ? VTlo : VThi;
      glds16(&vsrc[(h * 64 + l) * N + j0g + cj * 8], &Vs[buf][cj][h * 512]);
    }
    asm volatile("s_waitcnt vmcnt(0)" ::: "memory");
    __builtin_amdgcn_s_barrier();

    f32x4 acc[4];
#pragma unroll
    for (int ct = 0; ct < 4; ++ct) acc[ct] = (f32x4){0.f, 0.f, 0.f, 0.f};
#pragma unroll
    for (int kb = 0; kb < 4; ++kb) {
#pragma unroll
      for (int ct = 0; ct < 4; ++ct) {
        const bf16x8 kh = *(const bf16x8*)&Ks[0][kb * 4 + g][(ct * 16 + l15) * 8];
        const bf16x8 kl = *(const bf16x8*)&Ks[1][kb * 4 + g][(ct * 16 + l15) * 8];
        acc[ct] = __builtin_amdgcn_mfma_f32_16x16x32_bf16(qh[kb], kh, acc[ct], 0, 0, 0);
        acc[ct] = __builtin_amdgcn_mfma_f32_16x16x32_bf16(qh[kb], kl, acc[ct], 0, 0, 0);
        acc[ct] = __builtin_amdgcn_mfma_f32_16x16x32_bf16(ql[kb], kh, acc[ct], 0, 0, 0);
      }
    }

#pragma unroll
    for (int i = 0; i < 4; ++i) {
      float p[4];
      float s0 = acc[0][i] * adjm[i][0];
      float s1 = acc[1][i] * adjm[i][1];
      float s2 = acc[2][i] * adjm[i][2];
      float s3 = acc[3][i] * adjm[i][3];
      float t = fmaxf(fmaxf(s0, s1), fmaxf(s2, s3));
      t = fmaxf(t, __shfl_xor(t, 1));
      t = fmaxf(t, __shfl_xor(t, 2));
      t = fmaxf(t, __shfl_xor(t, 4));
      t = fmaxf(t, __shfl_xor(t, 8));
      float mn = fmaxf(m[i], t);
      float sc = __expf(m[i] - mn);
      p[0] = __expf(s0 - mn); p[1] = __expf(s1 - mn);
      p[2] = __expf(s2 - mn); p[3] = __expf(s3 - mn);
      float ps = p[0] + p[1] + p[2] + p[3];
      ps += __shfl_xor(ps, 1);
      ps += __shfl_xor(ps, 2);
      ps += __shfl_xor(ps, 4);
      ps += __shfl_xor(ps, 8);
      li[i] = li[i] * sc + ps;
      m[i] = mn;
#pragma unroll
      for (int nt = 0; nt < 8; ++nt) Xa[nt][i] *= sc;
      int row = 4 * ty + i;
#pragma unroll
      for (int ct = 0; ct < 4; ++ct) {
        float pe = p[ct];
        float po = __shfl_xor(pe, 1);
        int cj = ct * 2 + (tx16 >> 3);
        int e = (ct * 16 + tx16) & 7;
        unsigned int hpk = (__float_as_uint(po) & 0xffff0000u)
                         | (__float_as_uint(pe) >> 16);
        float pel = pe - hif(pe), pol = po - hif(po);
        unsigned int lpk = (__float_as_uint(pol) & 0xffff0000u)
                         | (__float_as_uint(pel) >> 16);
        if (!(tx16 & 1)) {
          *(unsigned int*)&Ps[0][cj][row * 8 + e] = hpk;
          *(unsigned int*)&Ps[1][cj][row * 8 + e] = lpk;
        }
      }
    }
    asm volatile("s_waitcnt lgkmcnt(0)" ::: "memory");  // own P writes complete

#pragma unroll
    for (int jb = 0; jb < 2; ++jb) {
      const bf16x8 ph = *(const bf16x8*)&Ps[0][jb * 4 + g][(16 * w + l15) * 8];
      const bf16x8 pl = *(const bf16x8*)&Ps[1][jb * 4 + g][(16 * w + l15) * 8];
#pragma unroll
      for (int nt = 0; nt < 8; ++nt) {
        const bf16x8 vh = *(const bf16x8*)&Vs[0][jb * 4 + g][(nt * 16 + l15) * 8];
        const bf16x8 vl = *(const bf16x8*)&Vs[1][jb * 4 + g][(nt * 16 + l15) * 8];
        Xa[nt] = __builtin_amdgcn_mfma_f32_16x16x32_bf16(ph, vh, Xa[nt], 0, 0, 0);
        Xa[nt] = __builtin_amdgcn_mfma_f32_16x16x32_bf16(ph, vl, Xa[nt], 0, 0, 0);
        Xa[nt] = __builtin_amdgcn_mfma_f32_16x16x32_bf16(pl, vh, Xa[nt], 0, 0, 0);
      }
    }
  }

#pragma unroll
  for (int i = 0; i < 4; ++i) {
    int row = i0 + 4 * ty + i;
    float inv = 1.f / li[i];
#pragma unroll
    for (int nt = 0; nt < 8; ++nt)
      xp[row * NH + nt * 16 + tx16] = Xa[nt][i] * inv;
    if (tx16 == 0) {
      ml[(cid * N + row) * 2 + 0] = m[i];
      ml[(cid * N + row) * 2 + 1] = li[i];
    }
  }
}

// ---------------------------------------------------------------------------
// k_comb: merge 8 chunk-partials, normalize, relu -> Xt
// ---------------------------------------------------------------------------
__global__ void k_comb(const float* __restrict__ xp0, const float* __restrict__ xp1,
                       const float* __restrict__ xp2, const float* __restrict__ xp3,
                       const float* __restrict__ xp4, const float* __restrict__ xp5,
                       const float* __restrict__ xp6, const float* __restrict__ xp7,
                       const float* __restrict__ ml, float* __restrict__ Xt) {
  int idx = blockIdx.x * 256 + threadIdx.x;
  int r = idx >> 5, d4 = (idx & 31) << 2;
  float mm[8], ll[8];
#pragma unroll
  for (int c = 0; c < 8; ++c) {
    mm[c] = ml[(c * N + r) * 2 + 0];
    ll[c] = ml[(c * N + r) * 2 + 1];
  }
  float ms = mm[0];
#pragma unroll
  for (int c = 1; c < 8; ++c) ms = fmaxf(ms, mm[c]);
  float e[8], den = 0.f;
#pragma unroll
  for (int c = 0; c < 8; ++c) { e[c] = __expf(mm[c] - ms); den += e[c] * ll[c]; }
  float inv = 1.f / den;
  const float4 a0 = *(const float4*)&xp0[r * NH + d4];
  const float4 a1 = *(const float4*)&xp1[r * NH + d4];
  const float4 a2 = *(const float4*)&xp2[r * NH + d4];
  const float4 a3 = *(const float4*)&xp3[r * NH + d4];
  const float4 a4 = *(const float4*)&xp4[r * NH + d4];
  const float4 a5 = *(const float4*)&xp5[r * NH + d4];
  const float4 a6 = *(const float4*)&xp6[r * NH + d4];
  const float4 a7 = *(const float4*)&xp7[r * NH + d4];
  float4 o;
  o.x = a0.x * e[0] + a1.x * e[1] + a2.x * e[2] + a3.x * e[3]
      + a4.x * e[4] + a5.x * e[5] + a6.x * e[6] + a7.x * e[7];
  o.y = a0.y * e[0] + a1.y * e[1] + a2.y * e[2] + a3.y * e[3]
      + a4.y * e[4] + a5.y * e[5] + a6.y * e[6] + a7.y * e[7];
  o.z = a0.z * e[0] + a1.z * e[1] + a2.z * e[2] + a3.z * e[3]
      + a4.z * e[4] + a5.z * e[5] + a6.z * e[6] + a7.z * e[7];
  o.w = a0.w * e[0] + a1.w * e[1] + a2.w * e[2] + a3.w * e[3]
      + a4.w * e[4] + a5.w * e[5] + a6.w * e[6] + a7.w * e[7];
  o.x = fmaxf(o.x * inv, 0.f); o.y = fmaxf(o.y * inv, 0.f);
  o.z = fmaxf(o.z * inv, 0.f); o.w = fmaxf(o.w * inv, 0.f);
  *(float4*)&Xt[r * NH + d4] = o;
}

// ---------------------------------------------------------------------------
// k_xtw2: xtw2 = Xt @ W2.  16 rows/block, 256 blocks, 256 threads.
// ---------------------------------------------------------------------------
__global__ __launch_bounds__(256) void k_xtw2(const float* __restrict__ Xt,
                                              const float* __restrict__ W2,
                                              float* __restrict__ xtw2) {
  __shared__ float xs[16 * 132];
  __shared__ float w2s[NH * NC];
  int i0 = blockIdx.x * 16;
  int tid = threadIdx.x;
#pragma unroll
  for (int s = 0; s < 2; ++s) {
    int f4 = tid + 256 * s;
    int r = f4 >> 5, k4 = (f4 & 31) << 2;
    const float4 v = *(const float4*)&Xt[(i0 + r) * NH + k4];
    *(float4*)&xs[r * 132 + k4] = v;
    *(float4*)&w2s[f4 * 4] = *(const float4*)&W2[f4 * 4];
  }
  __syncthreads();
  int r = tid >> 4, c = tid & 15;
  float acc = 0.f;
#pragma unroll 8
  for (int k = 0; k < NH; ++k)
    acc += xs[r * 132 + k] * w2s[k * NC + c];
  xtw2[(i0 + r) * NC + c] = acc;
}

// ---------------------------------------------------------------------------
// k_z: z = adj @ xtw2 + b2; out = rowsoftmax(z).  BM=8, 512 blocks.
// ---------------------------------------------------------------------------
__global__ __launch_bounds__(256) void k_z(const float* __restrict__ adj,
                                           const float* __restrict__ xtw2,
                                           const float* __restrict__ b2,
                                           float* __restrict__ out) {
  __shared__ float xwsT[16 * 68];
  int i0 = blockIdx.x * 8;
  int tid = threadIdx.x;
  int ty = tid >> 6, cg = (tid >> 4) & 3, jg = tid & 15;
  int jr = tid >> 2, cq = tid & 3;
  float acc[2][4];
#pragma unroll
  for (int i = 0; i < 2; ++i)
#pragma unroll
    for (int c = 0; c < 4; ++c) acc[i][c] = 0.f;

  for (int j0 = 0; j0 < N; j0 += 64) {
    float4 av[2];
#pragma unroll
    for (int i = 0; i < 2; ++i)
      av[i] = *(const float4*)&adj[(i0 + 2 * ty + i) * N + j0 + 4 * jg];
    const float4 xv = *(const float4*)&xtw2[(j0 + jr) * NC + 4 * cq];
    __syncthreads();
    xwsT[(4 * cq + 0) * 68 + jr] = xv.x;
    xwsT[(4 * cq + 1) * 68 + jr] = xv.y;
    xwsT[(4 * cq + 2) * 68 + jr] = xv.z;
    xwsT[(4 * cq + 3) * 68 + jr] = xv.w;
    __syncthreads();
#pragma unroll
    for (int c = 0; c < 4; ++c) {
      const float4 wv = *(const float4*)&xwsT[(4 * cg + c) * 68 + 4 * jg];
#pragma unroll
      for (int i = 0; i < 2; ++i)
        acc[i][c] += av[i].x * wv.x + av[i].y * wv.y
                   + av[i].z * wv.z + av[i].w * wv.w;
    }
  }
#pragma unroll
  for (int i = 0; i < 2; ++i)
#pragma unroll
    for (int c = 0; c < 4; ++c) {
      float v = acc[i][c];
      v += __shfl_xor(v, 1);
      v += __shfl_xor(v, 2);
      v += __shfl_xor(v, 4);
      v += __shfl_xor(v, 8);
      acc[i][c] = v;
    }
  float bv0 = b2[4 * cg + 0], bv1 = b2[4 * cg + 1];
  float bv2 = b2[4 * cg + 2], bv3 = b2[4 * cg + 3];
#pragma unroll
  for (int i = 0; i < 2; ++i) {
    float z0 = acc[i][0] + bv0, z1 = acc[i][1] + bv1;
    float z2 = acc[i][2] + bv2, z3 = acc[i][3] + bv3;
    float mv = fmaxf(fmaxf(z0, z1), fmaxf(z2, z3));
    mv = fmaxf(mv, __shfl_xor(mv, 16));
    mv = fmaxf(mv, __shfl_xor(mv, 32));
    float e0 = __expf(z0 - mv), e1 = __expf(z1 - mv);
    float e2 = __expf(z2 - mv), e3 = __expf(z3 - mv);
    float s = e0 + e1 + e2 + e3;
    s += __shfl_xor(s, 16);
    s += __shfl_xor(s, 32);
    if (jg == 0) {
      float4 o = {e0 / s, e1 / s, e2 / s, e3 / s};
      *(float4*)&out[(i0 + 2 * ty + i) * NC + 4 * cg] = o;
    }
  }
}

// ---------------------------------------------------------------------------
extern "C" void kernel_launch(void* const* d_in, const int* in_sizes, int n_in,
                              void* d_out, int out_size, void* d_ws, size_t ws_size,
                              hipStream_t stream) {
  const float* A0  = (const float*)d_in[0];
  const float* A1  = (const float*)d_in[1];
  const float* A2  = (const float*)d_in[2];
  const float* x   = (const float*)d_in[3];
  const float* Wa1 = (const float*)d_in[4];  const float* ba1 = (const float*)d_in[5];
  const float* Wa2 = (const float*)d_in[6];  const float* ba2 = (const float*)d_in[7];
  const float* Wa3 = (const float*)d_in[8];  const float* ba3 = (const float*)d_in[9];
  const float* Wagg = (const float*)d_in[10]; const float* bagg = (const float*)d_in[11];
  const float* W1  = (const float*)d_in[12]; const float* b1  = (const float*)d_in[13];
  const float* Wq  = (const float*)d_in[14]; const float* bq  = (const float*)d_in[15];
  const float* Wk  = (const float*)d_in[16]; const float* bk  = (const float*)d_in[17];
  const float* Wv  = (const float*)d_in[18]; const float* bv  = (const float*)d_in[19];
  const float* W2  = (const float*)d_in[20]; const float* b2  = (const float*)d_in[21];

  float* out0 = (float*)d_out;            // [N,16] class softmax
  float* nz   = out0 + N * NC;            // [N,3] mixing weights (output 1)

  float* ws   = (float*)d_ws;
  float* adj  = ws;                       // N*N
  float* Wc2  = adj + (size_t)N * N;      // 3*N*4
  float* bz   = Wc2 + 3 * N * 4;          // 16
  float* xw1  = bz + 16;                  // N*NH region -> xw1T bf16 / attn xp0
  float* hpre = xw1 + N * NH;             // N*NH  (h partial 0 / attn xp1)
  float* QhT  = hpre + N * NH;            // N*NH region: zp | W1T planes | Qhi/Qlo
  float* KhT  = QhT + N * NH;             // N*NH region -> Khi/Klo bf16
  float* Vh   = KhT + N * NH;             // N*NH region -> VThi/VTlo bf16
  float* Xt   = Vh + N * NH;              // N*NH  (H planes, then attn xp7/Xt)
  float* xtw2 = Xt + N * NH;              // N*NC  (WT planes, then xtw2)
  float* P2   = xtw2 + N * NC;            // h partial 1 / attn xp2
  float* P3   = P2 + N * NH;              // h partial 2 / attn xp3
  float* P4   = P3 + N * NH;              // h partial 3 / attn xp4
  float* P5   = P4 + N * NH;
  float* P6   = P5 + N * NH;
  float* ml   = P6 + N * NH;              // 8*N*2
  float* zp   = QhT;                      // [N][12] f32 = 192 KB (head of QhT)

  u16* xw1Thi = (u16*)xw1; u16* xw1Tlo = xw1Thi + (size_t)N * NH;
  u16* Qhi  = (u16*)QhT; u16* Qlo = Qhi + (size_t)N * NH;
  u16* Khi  = (u16*)KhT; u16* Klo = Khi + (size_t)N * NH;
  u16* VThi = (u16*)Vh;  u16* VTlo = VThi + (size_t)N * NH;
  u16* Hhi  = (u16*)Xt;  u16* Hlo = Hhi + (size_t)N * NH;
  u16* WThi = (u16*)xtw2; u16* WTlo = WThi + (size_t)3 * NH * NH;
  u16* W1Thi = (u16*)(QhT + 65536); u16* W1Tlo = W1Thi + (size_t)NF * NH;

  hipLaunchKernelGGL(k_wc, dim3(48), dim3(256), 0, stream,
                     Wa1, Wa2, Wa3, Wagg, ba1, ba2, ba3, bagg, Wc2, bz);
  hipLaunchKernelGGL(k_wsplit, dim3(448), dim3(256), 0, stream,
                     Wq, Wk, Wv, W1, WThi, WTlo, W1Thi, W1Tlo);
  hipLaunchKernelGGL(k_z4p, dim3(N / 4, 3), dim3(256), 0, stream,
                     A0, A1, A2, Wc2, zp);
  hipLaunchKernelGGL(k_nz, dim3(N / 256), dim3(256), 0, stream, zp, bz, nz);
  hipLaunchKernelGGL(k_adj, dim3(N * N / 4 / 256), dim3(256), 0, stream,
                     A0, A1, A2, nz, adj);
  hipLaunchKernelGGL(k_xw1m, dim3(N / 16), dim3(256), 0, stream,
                     x, W1Thi, W1Tlo, xw1Thi, xw1Tlo);
  hipLaunchKernelGGL(k_h, dim3(4, N / 64), dim3(512), 0, stream,
                     adj, xw1Thi, xw1Tlo, hpre, P2, P3, P4);
  hipLaunchKernelGGL(k_hsum, dim3(N * NH / 4 / 256), dim3(256), 0, stream,
                     hpre, P2, P3, P4, b1, Hhi, Hlo);
  hipLaunchKernelGGL(k_qkv2, dim3(N / 16), dim3(256), 0, stream,
                     Hhi, Hlo, WThi, WTlo, bq, bk, bv,
                     Qhi, Qlo, Khi, Klo, VThi, VTlo);
  hipLaunchKernelGGL(k_attn, dim3(CSPLIT, N / 128), dim3(512), 0, stream,
                     Qhi, Qlo, Khi, Klo, VThi, VTlo, adj,
                     xw1, hpre, P2, P3, P4, P5, P6, Xt, ml);
  hipLaunchKernelGGL(k_comb, dim3(N * NH / 4 / 256), dim3(256), 0, stream,
                     xw1, hpre, P2, P3, P4, P5, P6, Xt, ml, Xt);
  hipLaunchKernelGGL(k_xtw2, dim3(N / 16), dim3(256), 0, stream, Xt, W2, xtw2);
  hipLaunchKernelGGL(k_z, dim3(N / 8), dim3(256), 0, stream, adj, xtw2, b2, out0);
}